// Round 3
// baseline (7540.144 us; speedup 1.0000x reference)
//
#include <hip/hip_runtime.h>
#include <stdint.h>

// ---------------------------------------------------------------------------
// RPN proposal generation (decode + per-level topk + NMS + final topk)
// ---------------------------------------------------------------------------

constexpr int NIMG = 16;
constexpr int NLVL = 5;
constexpr int ATOT = 261888;
__device__ constexpr int LVL_N[5]   = {196608, 49152, 12288, 3072, 768};
__device__ constexpr int LVL_OFF[5] = {0, 196608, 245760, 258048, 261120};
__device__ constexpr int LVL_K[5]   = {2000, 2000, 2000, 2000, 768};
__device__ constexpr int CAT_OFF[5] = {0, 2000, 4000, 6000, 8000};
constexpr int TOTK = 8768;          // 4*2000 + 768
constexpr int FINAL_K = 1000;
constexpr float NEGV = -1000000000.0f;
constexpr float CLIPV = 4.135166556742356f;   // log(1000/16)
constexpr float IMGSZ = 1024.0f;
constexpr float NMS_T = 0.7f;

#define T_BLK 256

// ordered-uint mapping: monotone with float value
__device__ inline unsigned ordf(float f) {
    unsigned u = __float_as_uint(f);
    return (u & 0x80000000u) ? ~u : (u | 0x80000000u);
}

__device__ inline unsigned long long make_key(float sc, int idx) {
    return (((unsigned long long)ordf(sc)) << 32) | (unsigned long long)(0xFFFFFFFFu - (unsigned)idx);
}

// decode + clip, faithful to reference float32 op order (no FMA contraction)
__device__ inline float4 decode_clip(const float4 an, const float4 dl) {
#pragma clang fp contract(off)
    float w  = an.z - an.x;
    float h  = an.w - an.y;
    float cx = an.x + 0.5f * w;
    float cy = an.y + 0.5f * h;
    float dw = fminf(dl.z, CLIPV);
    float dh = fminf(dl.w, CLIPV);
    float pcx = dl.x * w + cx;
    float pcy = dl.y * h + cy;
    float pw  = expf(dw) * w;
    float ph  = expf(dh) * h;
    float x1 = pcx - 0.5f * pw;
    float y1 = pcy - 0.5f * ph;
    float x2 = pcx + 0.5f * pw;
    float y2 = pcy + 0.5f * ph;
    x1 = fminf(fmaxf(x1, 0.0f), IMGSZ);
    x2 = fminf(fmaxf(x2, 0.0f), IMGSZ);
    y1 = fminf(fmaxf(y1, 0.0f), IMGSZ);
    y2 = fminf(fmaxf(y2, 0.0f), IMGSZ);
    return make_float4(x1, y1, x2, y2);
}

__device__ inline bool iou_over(const float4 a, float areaA, const float4 b) {
#pragma clang fp contract(off)
    float ltx = fmaxf(a.x, b.x);
    float lty = fmaxf(a.y, b.y);
    float rbx = fminf(a.z, b.z);
    float rby = fminf(a.w, b.w);
    float w = fmaxf(rbx - ltx, 0.0f);
    float h = fmaxf(rby - lty, 0.0f);
    float inter = w * h;
    float areaB = (b.z - b.x) * (b.w - b.y);
    float iou = inter / (((areaA + areaB) - inter) + 1e-9f);
    return iou > NMS_T;
}

// Exact top-k (sorted desc, ties -> lower index) via 8-pass byte radix select
// over distinct 64-bit keys, then compact + bitonic sort in LDS.
// buf must hold P entries; P is pow2 >= k. Result: buf sorted ASCENDING; the
// top-k in descending order are buf[P-1], buf[P-2], ..., buf[P-k].
__device__ void radix_topk_sorted(const float* __restrict__ s, int n, int k, int P,
                                  unsigned* hist, unsigned long long* buf,
                                  unsigned long long* bcast, int* ibcast)
{
    const int tid = threadIdx.x;
    unsigned long long pref = 0ull;   // known high bytes of the k-th largest key
    int remk = k;

    for (int p = 7; p >= 0; --p) {
        for (int b = tid; b < 256; b += T_BLK) hist[b] = 0u;
        __syncthreads();
        // mask of the already-resolved high bytes (strictly above byte p)
        const unsigned long long himask =
            (p == 7) ? 0ull : (~0ull << (8 * (p + 1)));
        for (int i = tid; i < n; i += T_BLK) {
            unsigned long long kk = make_key(s[i], i);
            if ((kk & himask) == (pref & himask))
                atomicAdd(&hist[(unsigned)(kk >> (8 * p)) & 0xFFu], 1u);
        }
        __syncthreads();
        if (tid == 0) {
            int cum = 0, chosen = 0;
            for (int b = 255; b >= 0; --b) {
                int c = (int)hist[b];
                if (cum + c >= remk) { chosen = b; break; }
                cum += c;
            }
            bcast[0] = pref | (((unsigned long long)(unsigned)chosen) << (8 * p));
            ibcast[0] = remk - cum;
        }
        __syncthreads();
        pref = bcast[0];
        remk = ibcast[0];
    }
    const unsigned long long thresh = pref;   // exact key of the k-th largest

    if (tid == 0) ibcast[1] = 0;
    __syncthreads();
    for (int i = tid; i < n; i += T_BLK) {
        unsigned long long kk = make_key(s[i], i);
        if (kk >= thresh) {
            int pos = atomicAdd(&ibcast[1], 1);
            if (pos < P) buf[pos] = kk;
        }
    }
    __syncthreads();
    for (int i = k + tid; i < P; i += T_BLK) buf[i] = 0ull;
    __syncthreads();

    // bitonic sort ascending over P elements
    for (int sz = 2; sz <= P; sz <<= 1) {
        for (int st = sz >> 1; st > 0; st >>= 1) {
            for (int i = tid; i < P; i += T_BLK) {
                int j = i ^ st;
                if (j > i) {
                    unsigned long long a = buf[i];
                    unsigned long long b = buf[j];
                    bool up = ((i & sz) == 0);
                    if ((a > b) == up) { buf[i] = b; buf[j] = a; }
                }
            }
            __syncthreads();
        }
    }
}

// ---------------------------------------------------------------------------
// Kernel 1: per-(image,level) top-k + decode + clip
// ---------------------------------------------------------------------------
__global__ __launch_bounds__(T_BLK) void topk_level_kernel(
    const float* __restrict__ obj, const float4* __restrict__ deltas,
    const float4* __restrict__ anchors,
    float4* __restrict__ boxes_ws, float* __restrict__ scores_ws)
{
    const int img = blockIdx.x / NLVL;
    const int lvl = blockIdx.x % NLVL;
    const int n   = LVL_N[lvl];
    const int off = LVL_OFF[lvl];
    const int k   = LVL_K[lvl];
    const int P   = (k <= 1024) ? 1024 : 2048;

    const float* s = obj + (size_t)img * ATOT + off;

    __shared__ unsigned hist[256];
    __shared__ unsigned long long buf[2048];
    __shared__ unsigned long long bcast;
    __shared__ int ibcast[2];

    radix_topk_sorted(s, n, k, P, hist, buf, &bcast, ibcast);

    const int tid = threadIdx.x;
    const size_t outbase = (size_t)img * TOTK + CAT_OFF[lvl];
    for (int r = tid; r < k; r += T_BLK) {
        unsigned long long kk = buf[P - 1 - r];
        int li = (int)(0xFFFFFFFFu - (unsigned)(kk & 0xFFFFFFFFull));
        int g  = off + li;
        float sc  = s[li];
        float4 an = anchors[g];
        float4 dl = deltas[(size_t)img * ATOT + g];
        boxes_ws[outbase + r]  = decode_clip(an, dl);
        scores_ws[outbase + r] = sc;
    }
}

// ---------------------------------------------------------------------------
// Kernel 2: greedy NMS per (image,level); one wave per problem.
// Suppression bitmask distributed across lanes: lane l owns 64-bit word l
// (bits [64l, 64l+64)). Forward suppression == reference's backward scan.
// ---------------------------------------------------------------------------
__global__ __launch_bounds__(64) void nms_kernel(
    const float4* __restrict__ boxes_ws, float* __restrict__ scores_ws)
{
    const int img = blockIdx.x / NLVL;
    const int lvl = blockIdx.x % NLVL;
    const int K   = LVL_K[lvl];
    const size_t base = (size_t)img * TOTK + CAT_OFF[lvl];
    const int lane = threadIdx.x;

    __shared__ float4 bs[2000];
    for (int i = lane; i < K; i += 64) bs[i] = boxes_ws[base + i];
    __syncthreads();

    unsigned long long myw = 0ull;   // lane l holds suppression bits [64l, 64l+64)

    for (int i = 0; i < K; ++i) {
        unsigned long long wi = __shfl(myw, i >> 6);
        bool suppressed = (wi >> (i & 63)) & 1ull;   // wave-uniform
        if (!suppressed) {
            float4 bi = bs[i];
            float areaA = (bi.z - bi.x) * (bi.w - bi.y);
            for (int jb = i + 1; jb < K; jb += 64) {
                int j = jb + lane;
                bool over = false;
                if (j < K) over = iou_over(bi, areaA, bs[j]);
                unsigned long long m = __ballot(over);
                int w0 = jb >> 6;
                int sh = jb & 63;
                if (lane == w0) myw |= (m << sh);
                if (sh && lane == (w0 + 1)) myw |= (m >> (64 - sh));
            }
        }
    }

    const int nch = (K + 63) >> 6;
    for (int c = 0; c < nch; ++c) {
        unsigned long long w = __shfl(myw, c);
        int r = c * 64 + lane;
        if (r < K && ((w >> lane) & 1ull)) scores_ws[base + r] = NEGV;
    }
}

// ---------------------------------------------------------------------------
// Kernel 3: per-image final top-1000 over the 8768 concatenated candidates
// ---------------------------------------------------------------------------
__global__ __launch_bounds__(T_BLK) void final_topk_kernel(
    const float4* __restrict__ boxes_ws, const float* __restrict__ scores_ws,
    float* __restrict__ out)
{
    const int img = blockIdx.x;
    const float* s = scores_ws + (size_t)img * TOTK;

    __shared__ unsigned hist[256];
    __shared__ unsigned long long buf[1024];
    __shared__ unsigned long long bcast;
    __shared__ int ibcast[2];

    radix_topk_sorted(s, TOTK, FINAL_K, 1024, hist, buf, &bcast, ibcast);

    const int tid = threadIdx.x;
    float4* outb = (float4*)out;               // fboxes: [16][1000][4]
    float*  outs = out + NIMG * FINAL_K * 4;   // fscores: [16][1000]
    for (int r = tid; r < FINAL_K; r += T_BLK) {
        unsigned long long kk = buf[1024 - 1 - r];
        int idx = (int)(0xFFFFFFFFu - (unsigned)(kk & 0xFFFFFFFFull));
        outb[img * FINAL_K + r] = boxes_ws[(size_t)img * TOTK + idx];
        outs[img * FINAL_K + r] = s[idx];
    }
}

// ---------------------------------------------------------------------------
extern "C" void kernel_launch(void* const* d_in, const int* in_sizes, int n_in,
                              void* d_out, int out_size, void* d_ws, size_t ws_size,
                              hipStream_t stream)
{
    const float*  obj     = (const float*)d_in[0];
    const float4* deltas  = (const float4*)d_in[1];
    const float4* anchors = (const float4*)d_in[2];
    float* out = (float*)d_out;

    // workspace layout: boxes [16][8768] float4, then scores [16][8768] float
    float4* boxes_ws  = (float4*)d_ws;
    float*  scores_ws = (float*)((char*)d_ws + (size_t)NIMG * TOTK * sizeof(float4));

    topk_level_kernel<<<NIMG * NLVL, T_BLK, 0, stream>>>(obj, deltas, anchors, boxes_ws, scores_ws);
    nms_kernel<<<NIMG * NLVL, 64, 0, stream>>>(boxes_ws, scores_ws);
    final_topk_kernel<<<NIMG, T_BLK, 0, stream>>>(boxes_ws, scores_ws, out);
}

// Round 4
// 1074.717 us; speedup vs baseline: 7.0159x; 7.0159x over previous
//
#include <hip/hip_runtime.h>
#include <stdint.h>

typedef unsigned long long u64;
typedef unsigned u32;

// ---------------------------------------------------------------------------
// RPN proposal generation (decode + per-level topk + NMS + final topk)
// ---------------------------------------------------------------------------

constexpr int NIMG = 16;
constexpr int NLVL = 5;
constexpr int ATOT = 261888;
__device__ constexpr int LVL_N[5]   = {196608, 49152, 12288, 3072, 768};
__device__ constexpr int LVL_OFF[5] = {0, 196608, 245760, 258048, 261120};
__device__ constexpr int LVL_K[5]   = {2000, 2000, 2000, 2000, 768};
__device__ constexpr int CAT_OFF[5] = {0, 2000, 4000, 6000, 8000};
constexpr int TOTK = 8768;          // 4*2000 + 768
constexpr int FINAL_K = 1000;
constexpr float NEGV = -1000000000.0f;
constexpr float CLIPV = 4.135166556742356f;   // log(1000/16)
constexpr float IMGSZ = 1024.0f;
constexpr float NMS_T = 0.7f;
constexpr int MAXK = 2000;
constexpr int MW   = 32;            // mask row stride in u64 words (ceil(2000/64))

#define T_BLK 256

// ordered-uint mapping: monotone with float value
__device__ inline unsigned ordf(float f) {
    unsigned u = __float_as_uint(f);
    return (u & 0x80000000u) ? ~u : (u | 0x80000000u);
}

__device__ inline u64 make_key(float sc, int idx) {
    return (((u64)ordf(sc)) << 32) | (u64)(0xFFFFFFFFu - (unsigned)idx);
}

// decode + clip, faithful to reference float32 op order (no FMA contraction)
__device__ inline float4 decode_clip(const float4 an, const float4 dl) {
#pragma clang fp contract(off)
    float w  = an.z - an.x;
    float h  = an.w - an.y;
    float cx = an.x + 0.5f * w;
    float cy = an.y + 0.5f * h;
    float dw = fminf(dl.z, CLIPV);
    float dh = fminf(dl.w, CLIPV);
    float pcx = dl.x * w + cx;
    float pcy = dl.y * h + cy;
    float pw  = expf(dw) * w;
    float ph  = expf(dh) * h;
    float x1 = pcx - 0.5f * pw;
    float y1 = pcy - 0.5f * ph;
    float x2 = pcx + 0.5f * pw;
    float y2 = pcy + 0.5f * ph;
    x1 = fminf(fmaxf(x1, 0.0f), IMGSZ);
    x2 = fminf(fmaxf(x2, 0.0f), IMGSZ);
    y1 = fminf(fmaxf(y1, 0.0f), IMGSZ);
    y2 = fminf(fmaxf(y2, 0.0f), IMGSZ);
    return make_float4(x1, y1, x2, y2);
}

__device__ inline bool iou_over(const float4 a, float areaA, const float4 b) {
#pragma clang fp contract(off)
    float ltx = fmaxf(a.x, b.x);
    float lty = fmaxf(a.y, b.y);
    float rbx = fminf(a.z, b.z);
    float rby = fminf(a.w, b.w);
    float w = fmaxf(rbx - ltx, 0.0f);
    float h = fmaxf(rby - lty, 0.0f);
    float inter = w * h;
    float areaB = (b.z - b.x) * (b.w - b.y);
    float iou = inter / (((areaA + areaB) - inter) + 1e-9f);
    return iou > NMS_T;
}

// ---------------------------------------------------------------------------
// Exact top-k threshold via 11-bit-digit radix select over distinct 64-bit
// keys, with early exit when the boundary bin count equals the remaining k
// (then all lower key bits are irrelevant: #items >= prefix is exactly k).
// Then compact + bitonic sort. buf sorted ASCENDING; top-k desc are
// buf[P-1], ..., buf[P-k]. Requires n % 4 == 0 and 16B-aligned s.
// ---------------------------------------------------------------------------
__device__ void radix_topk_sorted(const float* __restrict__ s, int n, int k, int P,
                                  u32* hist /*[4*2048]*/, u32* chunk /*[256]*/,
                                  u64* buf, u64* bcast, int* ibcast)
{
    const int tid = threadIdx.x;
    const int wid = tid >> 6;
    u64 pref = 0ull;
    int remk = k;
    int done = 0;
    const int SH[6] = {53, 42, 31, 20, 9, 0};
    const int WD[6] = {11, 11, 11, 11, 11, 9};

    for (int pass = 0; pass < 6 && !done; ++pass) {
        const int shift = SH[pass];
        const int nb    = 1 << WD[pass];
        for (int b = tid; b < 4 * 2048; b += T_BLK) hist[b] = 0u;
        __syncthreads();
        const u64 himask = (pass == 0) ? 0ull : (~0ull << SH[pass - 1]);
        u32* myh = hist + wid * 2048;
        for (int i0 = tid * 4; i0 < n; i0 += T_BLK * 4) {
            float4 v = *(const float4*)(s + i0);
            u64 k0 = make_key(v.x, i0);
            u64 k1 = make_key(v.y, i0 + 1);
            u64 k2 = make_key(v.z, i0 + 2);
            u64 k3 = make_key(v.w, i0 + 3);
            if ((k0 & himask) == pref) atomicAdd(&myh[(u32)(k0 >> shift) & (nb - 1)], 1u);
            if ((k1 & himask) == pref) atomicAdd(&myh[(u32)(k1 >> shift) & (nb - 1)], 1u);
            if ((k2 & himask) == pref) atomicAdd(&myh[(u32)(k2 >> shift) & (nb - 1)], 1u);
            if ((k3 & himask) == pref) atomicAdd(&myh[(u32)(k3 >> shift) & (nb - 1)], 1u);
        }
        __syncthreads();
        // per-thread 8-bin chunk sums (over the 4 wave copies)
        u32 csum = 0;
        for (int b = tid * 8; b < tid * 8 + 8; ++b)
            if (b < nb) csum += hist[b] + hist[2048 + b] + hist[4096 + b] + hist[6144 + b];
        chunk[tid] = csum;
        __syncthreads();
        if (tid == 0) {
            int cum = 0, cidx = 0;
            for (int c = 255; c >= 0; --c) {
                int cs = (int)chunk[c];
                if (cum + cs >= remk) { cidx = c; break; }
                cum += cs;
            }
            for (int b = cidx * 8 + 7; b >= cidx * 8; --b) {
                if (b >= nb) continue;
                int cb = (int)(hist[b] + hist[2048 + b] + hist[4096 + b] + hist[6144 + b]);
                if (cum + cb >= remk) {
                    bcast[0]  = pref | (((u64)(u32)b) << shift);
                    ibcast[0] = remk - cum;
                    ibcast[1] = (cb == (remk - cum)) ? 1 : 0;
                    break;
                }
                cum += cb;
            }
        }
        __syncthreads();
        pref = bcast[0];
        remk = ibcast[0];
        done = ibcast[1];
        __syncthreads();
    }
    const u64 thresh = pref;   // exactly k keys are >= thresh

    if (tid == 0) ibcast[2] = 0;
    __syncthreads();
    for (int i0 = tid * 4; i0 < n; i0 += T_BLK * 4) {
        float4 v = *(const float4*)(s + i0);
        u64 kk[4] = { make_key(v.x, i0), make_key(v.y, i0 + 1),
                      make_key(v.z, i0 + 2), make_key(v.w, i0 + 3) };
        #pragma unroll
        for (int q = 0; q < 4; ++q) {
            if (kk[q] >= thresh) {
                int pos = atomicAdd(&ibcast[2], 1);
                if (pos < P) buf[pos] = kk[q];
            }
        }
    }
    __syncthreads();
    for (int i = k + tid; i < P; i += T_BLK) buf[i] = 0ull;
    __syncthreads();

    // bitonic sort ascending over P elements
    for (int sz = 2; sz <= P; sz <<= 1) {
        for (int st = sz >> 1; st > 0; st >>= 1) {
            for (int i = tid; i < P; i += T_BLK) {
                int j = i ^ st;
                if (j > i) {
                    u64 a = buf[i];
                    u64 b = buf[j];
                    bool up = ((i & sz) == 0);
                    if ((a > b) == up) { buf[i] = b; buf[j] = a; }
                }
            }
            __syncthreads();
        }
    }
}

// ---------------------------------------------------------------------------
// Kernel 1: per-(image,level) top-k + decode + clip
// ---------------------------------------------------------------------------
__global__ __launch_bounds__(T_BLK) void topk_level_kernel(
    const float* __restrict__ obj, const float4* __restrict__ deltas,
    const float4* __restrict__ anchors,
    float4* __restrict__ boxes_ws, float* __restrict__ scores_ws)
{
    const int img = blockIdx.x / NLVL;
    const int lvl = blockIdx.x % NLVL;
    const int n   = LVL_N[lvl];
    const int off = LVL_OFF[lvl];
    const int k   = LVL_K[lvl];
    const int P   = (k <= 1024) ? 1024 : 2048;

    const float* s = obj + (size_t)img * ATOT + off;

    __shared__ u32 hist[4 * 2048];
    __shared__ u32 chunk[256];
    __shared__ u64 buf[2048];
    __shared__ u64 bcast;
    __shared__ int ibcast[4];

    radix_topk_sorted(s, n, k, P, hist, chunk, buf, &bcast, ibcast);

    const int tid = threadIdx.x;
    const size_t outbase = (size_t)img * TOTK + CAT_OFF[lvl];
    for (int r = tid; r < k; r += T_BLK) {
        u64 kk = buf[P - 1 - r];
        int li = (int)(0xFFFFFFFFu - (unsigned)(kk & 0xFFFFFFFFull));
        int g  = off + li;
        float sc  = s[li];
        float4 an = anchors[g];
        float4 dl = deltas[(size_t)img * ATOT + g];
        boxes_ws[outbase + r]  = decode_clip(an, dl);
        scores_ws[outbase + r] = sc;
    }
}

// ---------------------------------------------------------------------------
// Kernel 2a (fast path): full pairwise IoU>thresh bitmask, upper triangle.
// mask[p][i][w] bit l  <=>  IoU(box_i, box_j=w*64+l) > 0.7, for j > i.
// Grid: 80 problems x 32 row-tiles of 64 rows; 256 threads (4 waves x 16 rows).
// ---------------------------------------------------------------------------
__global__ __launch_bounds__(T_BLK) void nms_mask_kernel(
    const float4* __restrict__ boxes_ws, u64* __restrict__ mask)
{
    const int p    = blockIdx.x >> 5;
    const int tile = blockIdx.x & 31;
    const int img  = p / NLVL;
    const int lvl  = p % NLVL;
    const int K    = LVL_K[lvl];
    const int W    = (K + 63) >> 6;
    if (tile >= W) return;               // uniform across block, before any barrier

    __shared__ float4 bs[MAXK];
    const size_t base = (size_t)img * TOTK + CAT_OFF[lvl];
    for (int i = threadIdx.x; i < K; i += T_BLK) bs[i] = boxes_ws[base + i];
    __syncthreads();

    const int lane = threadIdx.x & 63;
    const int wid  = threadIdx.x >> 6;
    u64* rowbase = mask + (size_t)p * MAXK * MW;

    for (int r = 0; r < 16; ++r) {
        const int i = tile * 64 + wid * 16 + r;
        if (i >= K) break;               // wave-uniform
        const float4 bi = bs[i];
        const float areaA = (bi.z - bi.x) * (bi.w - bi.y);
        for (int w = i >> 6; w < W; ++w) {
            const int j = w * 64 + lane;
            bool over = false;
            if (j > i && j < K) over = iou_over(bi, areaA, bs[j]);
            u64 m = __ballot(over);
            if (lane == 0) rowbase[(size_t)i * MW + w] = m;
        }
    }
}

// ---------------------------------------------------------------------------
// Kernel 2b (fast path): serial greedy scan over precomputed mask rows.
// One wave per problem; lane l owns suppression word l; 16-deep register
// prefetch of mask rows (K divisible by 16 for all levels).
// ---------------------------------------------------------------------------
__global__ __launch_bounds__(64) void nms_scan_kernel(
    const u64* __restrict__ mask, float* __restrict__ scores_ws)
{
    const int p   = blockIdx.x;
    const int img = p / NLVL;
    const int lvl = p % NLVL;
    const int K   = LVL_K[lvl];
    const int W   = (K + 63) >> 6;
    const int lane = threadIdx.x;
    const u64* rowp = mask + (size_t)p * MAXK * MW + lane;

    u64 supp = 0ull;

#define LDROW(i) ((lane < MW) ? rowp[(size_t)(((i) < K) ? (i) : (K - 1)) * MW] : 0ull)
    u64 m0  = LDROW(0),  m1  = LDROW(1),  m2  = LDROW(2),  m3  = LDROW(3);
    u64 m4  = LDROW(4),  m5  = LDROW(5),  m6  = LDROW(6),  m7  = LDROW(7);
    u64 m8  = LDROW(8),  m9  = LDROW(9),  m10 = LDROW(10), m11 = LDROW(11);
    u64 m12 = LDROW(12), m13 = LDROW(13), m14 = LDROW(14), m15 = LDROW(15);

#define STEP(idx, mr) {                                        \
        const int w0 = (idx) >> 6;                             \
        u64 cw = __shfl(supp, w0);                             \
        if (!((cw >> ((idx) & 63)) & 1ull))                    \
            supp |= (lane >= w0) ? mr : 0ull;                  \
        mr = LDROW((idx) + 16); }

    for (int i = 0; i < K; i += 16) {
        STEP(i + 0,  m0);  STEP(i + 1,  m1);  STEP(i + 2,  m2);  STEP(i + 3,  m3);
        STEP(i + 4,  m4);  STEP(i + 5,  m5);  STEP(i + 6,  m6);  STEP(i + 7,  m7);
        STEP(i + 8,  m8);  STEP(i + 9,  m9);  STEP(i + 10, m10); STEP(i + 11, m11);
        STEP(i + 12, m12); STEP(i + 13, m13); STEP(i + 14, m14); STEP(i + 15, m15);
    }
#undef STEP
#undef LDROW

    const size_t base = (size_t)img * TOTK + CAT_OFF[lvl];
    for (int c = 0; c < W; ++c) {
        u64 w = __shfl(supp, c);
        int r = c * 64 + lane;
        if (r < K && ((w >> lane) & 1ull)) scores_ws[base + r] = NEGV;
    }
}

// ---------------------------------------------------------------------------
// Kernel 2 (fallback, ws too small): single-wave greedy NMS (proven correct)
// ---------------------------------------------------------------------------
__global__ __launch_bounds__(64) void nms_kernel(
    const float4* __restrict__ boxes_ws, float* __restrict__ scores_ws)
{
    const int img = blockIdx.x / NLVL;
    const int lvl = blockIdx.x % NLVL;
    const int K   = LVL_K[lvl];
    const size_t base = (size_t)img * TOTK + CAT_OFF[lvl];
    const int lane = threadIdx.x;

    __shared__ float4 bs[MAXK];
    for (int i = lane; i < K; i += 64) bs[i] = boxes_ws[base + i];
    __syncthreads();

    u64 myw = 0ull;
    for (int i = 0; i < K; ++i) {
        u64 wi = __shfl(myw, i >> 6);
        bool suppressed = (wi >> (i & 63)) & 1ull;
        if (!suppressed) {
            float4 bi = bs[i];
            float areaA = (bi.z - bi.x) * (bi.w - bi.y);
            for (int jb = i + 1; jb < K; jb += 64) {
                int j = jb + lane;
                bool over = false;
                if (j < K) over = iou_over(bi, areaA, bs[j]);
                u64 m = __ballot(over);
                int w0 = jb >> 6;
                int sh = jb & 63;
                if (lane == w0) myw |= (m << sh);
                if (sh && lane == (w0 + 1)) myw |= (m >> (64 - sh));
            }
        }
    }
    const int nch = (K + 63) >> 6;
    for (int c = 0; c < nch; ++c) {
        u64 w = __shfl(myw, c);
        int r = c * 64 + lane;
        if (r < K && ((w >> lane) & 1ull)) scores_ws[base + r] = NEGV;
    }
}

// ---------------------------------------------------------------------------
// Kernel 3: per-image final top-1000 over the 8768 concatenated candidates
// ---------------------------------------------------------------------------
__global__ __launch_bounds__(T_BLK) void final_topk_kernel(
    const float4* __restrict__ boxes_ws, const float* __restrict__ scores_ws,
    float* __restrict__ out)
{
    const int img = blockIdx.x;
    const float* s = scores_ws + (size_t)img * TOTK;

    __shared__ u32 hist[4 * 2048];
    __shared__ u32 chunk[256];
    __shared__ u64 buf[1024];
    __shared__ u64 bcast;
    __shared__ int ibcast[4];

    radix_topk_sorted(s, TOTK, FINAL_K, 1024, hist, chunk, buf, &bcast, ibcast);

    const int tid = threadIdx.x;
    float4* outb = (float4*)out;               // fboxes: [16][1000][4]
    float*  outs = out + NIMG * FINAL_K * 4;   // fscores: [16][1000]
    for (int r = tid; r < FINAL_K; r += T_BLK) {
        u64 kk = buf[1024 - 1 - r];
        int idx = (int)(0xFFFFFFFFu - (unsigned)(kk & 0xFFFFFFFFull));
        outb[img * FINAL_K + r] = boxes_ws[(size_t)img * TOTK + idx];
        outs[img * FINAL_K + r] = s[idx];
    }
}

// ---------------------------------------------------------------------------
extern "C" void kernel_launch(void* const* d_in, const int* in_sizes, int n_in,
                              void* d_out, int out_size, void* d_ws, size_t ws_size,
                              hipStream_t stream)
{
    const float*  obj     = (const float*)d_in[0];
    const float4* deltas  = (const float4*)d_in[1];
    const float4* anchors = (const float4*)d_in[2];
    float* out = (float*)d_out;

    // workspace layout: boxes [16][8768] float4 | scores [16][8768] f32 | mask
    float4* boxes_ws  = (float4*)d_ws;
    float*  scores_ws = (float*)((char*)d_ws + (size_t)NIMG * TOTK * sizeof(float4));
    size_t  used      = (size_t)NIMG * TOTK * (sizeof(float4) + sizeof(float));
    size_t  mask_off  = (used + 255) & ~(size_t)255;
    size_t  mask_b    = (size_t)NIMG * NLVL * MAXK * MW * sizeof(u64);   // ~41 MB

    topk_level_kernel<<<NIMG * NLVL, T_BLK, 0, stream>>>(obj, deltas, anchors, boxes_ws, scores_ws);

    if (ws_size >= mask_off + mask_b) {
        u64* mask = (u64*)((char*)d_ws + mask_off);
        nms_mask_kernel<<<NIMG * NLVL * 32, T_BLK, 0, stream>>>(boxes_ws, mask);
        nms_scan_kernel<<<NIMG * NLVL, 64, 0, stream>>>(mask, scores_ws);
    } else {
        nms_kernel<<<NIMG * NLVL, 64, 0, stream>>>(boxes_ws, scores_ws);
    }

    final_topk_kernel<<<NIMG, T_BLK, 0, stream>>>(boxes_ws, scores_ws, out);
}

// Round 5
// 999.172 us; speedup vs baseline: 7.5464x; 1.0756x over previous
//
#include <hip/hip_runtime.h>
#include <stdint.h>

typedef unsigned long long u64;
typedef unsigned u32;

// ---------------------------------------------------------------------------
// RPN proposal generation (decode + per-level topk + NMS + final topk)
// ---------------------------------------------------------------------------

constexpr int NIMG = 16;
constexpr int NLVL = 5;
constexpr int ATOT = 261888;
__device__ constexpr int LVL_N[5]   = {196608, 49152, 12288, 3072, 768};
__device__ constexpr int LVL_OFF[5] = {0, 196608, 245760, 258048, 261120};
__device__ constexpr int LVL_K[5]   = {2000, 2000, 2000, 2000, 768};
__device__ constexpr int CAT_OFF[5] = {0, 2000, 4000, 6000, 8000};
constexpr int TOTK = 8768;          // 4*2000 + 768
constexpr int FINAL_K = 1000;
constexpr float NEGV = -1000000000.0f;
constexpr float CLIPV = 4.135166556742356f;   // log(1000/16)
constexpr float IMGSZ = 1024.0f;
constexpr float NMS_T = 0.7f;
constexpr int MAXK = 2000;
constexpr int MW   = 32;            // mask row stride in u64 words (ceil(2000/64))

constexpr int NSLICE  = 65;         // per image: 48 + 12 + 3 + 1 + 1 (4096-item slices)
constexpr int NBIN    = 8192;       // 13-bit first-digit bins
constexpr int CANDCAP = 4096;       // per-problem candidate capacity

#define T_BLK 256

// ---------------- workspace layout (bytes) ----------------
constexpr size_t BOX_OFF    = 0;                                   // 16*8768*16
constexpr size_t SCORES_OFF = (size_t)NIMG * TOTK * 16;            // 2,244,608
constexpr size_t GHIST_OFF  = SCORES_OFF + (size_t)NIMG * TOTK * 4;// 2,805,760
constexpr size_t CNT_OFF    = GHIST_OFF + (size_t)NIMG * NLVL * NBIN * 4; // 5,427,200
constexpr size_t GB_OFF     = CNT_OFF + (size_t)NIMG * NLVL * 4;   // 5,427,520
constexpr size_t CAND_OFF   = GB_OFF + (size_t)NIMG * NLVL * 4;    // 5,427,840
constexpr size_t MASK_OFF   = ((CAND_OFF + (size_t)NIMG * NLVL * CANDCAP * 8) + 255) & ~(size_t)255;
constexpr size_t MASK_BYTES = (size_t)NIMG * NLVL * MAXK * MW * 8; // ~41 MB
constexpr int    ZERO_WORDS = NIMG * NLVL * NBIN + NIMG * NLVL;    // ghist + cand_cnt (contiguous)

// ordered-uint mapping: monotone with float value
__device__ inline unsigned ordf(float f) {
    unsigned u = __float_as_uint(f);
    return (u & 0x80000000u) ? ~u : (u | 0x80000000u);
}

__device__ inline u64 make_key(float sc, int idx) {
    return (((u64)ordf(sc)) << 32) | (u64)(0xFFFFFFFFu - (unsigned)idx);
}

// decode + clip, faithful to reference float32 op order (no FMA contraction)
__device__ inline float4 decode_clip(const float4 an, const float4 dl) {
#pragma clang fp contract(off)
    float w  = an.z - an.x;
    float h  = an.w - an.y;
    float cx = an.x + 0.5f * w;
    float cy = an.y + 0.5f * h;
    float dw = fminf(dl.z, CLIPV);
    float dh = fminf(dl.w, CLIPV);
    float pcx = dl.x * w + cx;
    float pcy = dl.y * h + cy;
    float pw  = expf(dw) * w;
    float ph  = expf(dh) * h;
    float x1 = pcx - 0.5f * pw;
    float y1 = pcy - 0.5f * ph;
    float x2 = pcx + 0.5f * pw;
    float y2 = pcy + 0.5f * ph;
    x1 = fminf(fmaxf(x1, 0.0f), IMGSZ);
    x2 = fminf(fmaxf(x2, 0.0f), IMGSZ);
    y1 = fminf(fmaxf(y1, 0.0f), IMGSZ);
    y2 = fminf(fmaxf(y2, 0.0f), IMGSZ);
    return make_float4(x1, y1, x2, y2);
}

__device__ inline bool iou_over(const float4 a, float areaA, const float4 b) {
#pragma clang fp contract(off)
    float ltx = fmaxf(a.x, b.x);
    float lty = fmaxf(a.y, b.y);
    float rbx = fminf(a.z, b.z);
    float rby = fminf(a.w, b.w);
    float w = fmaxf(rbx - ltx, 0.0f);
    float h = fmaxf(rby - lty, 0.0f);
    float inter = w * h;
    float areaB = (b.z - b.x) * (b.w - b.y);
    float iou = inter / (((areaA + areaB) - inter) + 1e-9f);
    return iou > NMS_T;
}

// slice id -> (lvl, offset-in-level, length); uniform per block
__device__ inline void slice_map(int sid, int& lvl, int& loff, int& len) {
    if (sid < 48)      { lvl = 0; loff = sid * 4096;        len = 4096; }
    else if (sid < 60) { lvl = 1; loff = (sid - 48) * 4096; len = 4096; }
    else if (sid < 63) { lvl = 2; loff = (sid - 60) * 4096; len = 4096; }
    else if (sid == 63){ lvl = 3; loff = 0;                 len = 3072; }
    else               { lvl = 4; loff = 0;                 len = 768;  }
}

// ---------------------------------------------------------------------------
// Kernel 0: zero ghist + cand_cnt
// ---------------------------------------------------------------------------
__global__ __launch_bounds__(T_BLK) void zero_kernel(u32* __restrict__ dst) {
    for (int i = blockIdx.x * T_BLK + threadIdx.x; i < ZERO_WORDS; i += gridDim.x * T_BLK)
        dst[i] = 0u;
}

// ---------------------------------------------------------------------------
// Kernel A: distributed 13-bit score histogram per (img,lvl)
// ---------------------------------------------------------------------------
__global__ __launch_bounds__(T_BLK) void hist_kernel(
    const float* __restrict__ obj, u32* __restrict__ ghist)
{
    const int img = blockIdx.x / NSLICE;
    const int sid = blockIdx.x % NSLICE;
    int lvl, loff, len;
    slice_map(sid, lvl, loff, len);
    const int p = img * NLVL + lvl;
    const float* s = obj + (size_t)img * ATOT + LVL_OFF[lvl] + loff;
    const int tid = threadIdx.x;

    __shared__ u32 hist[NBIN];
    for (int b = tid; b < NBIN; b += T_BLK) hist[b] = 0u;
    __syncthreads();

    for (int i0 = tid * 4; i0 < len; i0 += T_BLK * 4) {
        float4 v = *(const float4*)(s + i0);
        atomicAdd(&hist[ordf(v.x) >> 19], 1u);
        atomicAdd(&hist[ordf(v.y) >> 19], 1u);
        atomicAdd(&hist[ordf(v.z) >> 19], 1u);
        atomicAdd(&hist[ordf(v.w) >> 19], 1u);
    }
    __syncthreads();

    u32* gh = ghist + (size_t)p * NBIN;
    for (int b = tid; b < NBIN; b += T_BLK) {
        u32 v = hist[b];
        if (v) atomicAdd(&gh[b], v);
    }
}

// ---------------------------------------------------------------------------
// Kernel B: boundary bin per problem.  b* = max b with count(digit >= b) >= k.
// 256 threads: chunk = 32 bins each; parallel suffix scan over chunks.
// ---------------------------------------------------------------------------
__global__ __launch_bounds__(T_BLK) void bound_kernel(
    const u32* __restrict__ ghist, u32* __restrict__ gbound)
{
    const int p   = blockIdx.x;
    const int lvl = p % NLVL;
    const u32 k   = (u32)LVL_K[lvl];
    const u32* gh = ghist + (size_t)p * NBIN;
    const int tid = threadIdx.x;

    u32 ch = 0;
    for (int b = tid * 32; b < tid * 32 + 32; ++b) ch += gh[b];

    __shared__ u32 suf[T_BLK];
    suf[tid] = ch;
    __syncthreads();
    for (int d = 1; d < T_BLK; d <<= 1) {
        u32 add = (tid + d < T_BLK) ? suf[tid + d] : 0u;
        __syncthreads();
        suf[tid] += add;
        __syncthreads();
    }
    const u32 inc = suf[tid];                    // count(digit >= tid*32)
    if (inc >= k && inc - ch < k) {              // boundary chunk: exactly one thread
        u32 cum = inc - ch;                      // count above this chunk
        int bin = tid * 32;
        for (int b = tid * 32 + 31; b >= tid * 32; --b) {
            u32 hb = gh[b];
            if (cum + hb >= k) { bin = b; break; }
            cum += hb;
        }
        gbound[p] = (u32)bin;
    }
}

// ---------------------------------------------------------------------------
// Kernel C: compact candidate keys (digit >= boundary bin) per problem
// ---------------------------------------------------------------------------
__global__ __launch_bounds__(T_BLK) void compact_kernel(
    const float* __restrict__ obj, const u32* __restrict__ gbound,
    u32* __restrict__ cand_cnt, u64* __restrict__ cand)
{
    const int img = blockIdx.x / NSLICE;
    const int sid = blockIdx.x % NSLICE;
    int lvl, loff, len;
    slice_map(sid, lvl, loff, len);
    const int p = img * NLVL + lvl;
    const u32 bin = gbound[p];
    const float* s = obj + (size_t)img * ATOT + LVL_OFF[lvl] + loff;
    const int tid = threadIdx.x;
    u64* cp = cand + (size_t)p * CANDCAP;

    for (int i0 = tid * 4; i0 < len; i0 += T_BLK * 4) {
        float4 v = *(const float4*)(s + i0);
        float vv[4] = {v.x, v.y, v.z, v.w};
        #pragma unroll
        for (int q = 0; q < 4; ++q) {
            if ((ordf(vv[q]) >> 19) >= bin) {
                int pos = (int)atomicAdd(&cand_cnt[p], 1u);
                if (pos < CANDCAP) cp[pos] = make_key(vv[q], loff + i0 + q);
            }
        }
    }
}

// ---------------------------------------------------------------------------
// Kernel D: per-problem exact top-k (bitonic over candidates) + decode + clip
// ---------------------------------------------------------------------------
__global__ __launch_bounds__(T_BLK) void sort_decode_kernel(
    const float4* __restrict__ deltas, const float4* __restrict__ anchors,
    const u32* __restrict__ cand_cnt, const u64* __restrict__ cand,
    float4* __restrict__ boxes_ws, float* __restrict__ scores_ws)
{
    const int p   = blockIdx.x;
    const int img = p / NLVL;
    const int lvl = p % NLVL;
    const int k   = LVL_K[lvl];
    const int off = LVL_OFF[lvl];
    const int tid = threadIdx.x;
    const int cnt = min((int)cand_cnt[p], CANDCAP);
    const u64* cp = cand + (size_t)p * CANDCAP;

    __shared__ u64 buf[CANDCAP];
    for (int i = tid; i < CANDCAP; i += T_BLK) buf[i] = (i < cnt) ? cp[i] : 0ull;
    __syncthreads();

    // bitonic sort ascending over CANDCAP elements (keys distinct, 0-padded)
    for (int sz = 2; sz <= CANDCAP; sz <<= 1) {
        for (int st = sz >> 1; st > 0; st >>= 1) {
            for (int i = tid; i < CANDCAP; i += T_BLK) {
                int j = i ^ st;
                if (j > i) {
                    u64 a = buf[i];
                    u64 b = buf[j];
                    bool up = ((i & sz) == 0);
                    if ((a > b) == up) { buf[i] = b; buf[j] = a; }
                }
            }
            __syncthreads();
        }
    }

    const size_t outbase = (size_t)img * TOTK + CAT_OFF[lvl];
    for (int r = tid; r < k; r += T_BLK) {
        u64 kk = buf[CANDCAP - 1 - r];
        int li = (int)(0xFFFFFFFFu - (unsigned)(kk & 0xFFFFFFFFull));
        int g  = off + li;
        u32 hu = (u32)(kk >> 32);                // bit-exact score recovery
        u32 fu = (hu & 0x80000000u) ? (hu ^ 0x80000000u) : ~hu;
        float sc = __uint_as_float(fu);
        float4 an = anchors[g];
        float4 dl = deltas[(size_t)img * ATOT + g];
        boxes_ws[outbase + r]  = decode_clip(an, dl);
        scores_ws[outbase + r] = sc;
    }
}

// ---------------------------------------------------------------------------
// Kernel 2a: full pairwise IoU>thresh bitmask, upper triangle.
// ---------------------------------------------------------------------------
__global__ __launch_bounds__(T_BLK) void nms_mask_kernel(
    const float4* __restrict__ boxes_ws, u64* __restrict__ mask)
{
    const int p    = blockIdx.x >> 5;
    const int tile = blockIdx.x & 31;
    const int img  = p / NLVL;
    const int lvl  = p % NLVL;
    const int K    = LVL_K[lvl];
    const int W    = (K + 63) >> 6;
    if (tile >= W) return;               // uniform across block, before any barrier

    __shared__ float4 bs[MAXK];
    const size_t base = (size_t)img * TOTK + CAT_OFF[lvl];
    for (int i = threadIdx.x; i < K; i += T_BLK) bs[i] = boxes_ws[base + i];
    __syncthreads();

    const int lane = threadIdx.x & 63;
    const int wid  = threadIdx.x >> 6;
    u64* rowbase = mask + (size_t)p * MAXK * MW;

    for (int r = 0; r < 16; ++r) {
        const int i = tile * 64 + wid * 16 + r;
        if (i >= K) break;               // wave-uniform
        const float4 bi = bs[i];
        const float areaA = (bi.z - bi.x) * (bi.w - bi.y);
        for (int w = i >> 6; w < W; ++w) {
            const int j = w * 64 + lane;
            bool over = false;
            if (j > i && j < K) over = iou_over(bi, areaA, bs[j]);
            u64 m = __ballot(over);
            if (lane == 0) rowbase[(size_t)i * MW + w] = m;
        }
    }
}

// ---------------------------------------------------------------------------
// Kernel 2b: serial greedy scan over precomputed mask rows. One wave/problem.
// ---------------------------------------------------------------------------
__global__ __launch_bounds__(64) void nms_scan_kernel(
    const u64* __restrict__ mask, float* __restrict__ scores_ws)
{
    const int p   = blockIdx.x;
    const int img = p / NLVL;
    const int lvl = p % NLVL;
    const int K   = LVL_K[lvl];
    const int W   = (K + 63) >> 6;
    const int lane = threadIdx.x;
    const u64* rowp = mask + (size_t)p * MAXK * MW + lane;

    u64 supp = 0ull;

#define LDROW(i) ((lane < MW) ? rowp[(size_t)(((i) < K) ? (i) : (K - 1)) * MW] : 0ull)
    u64 m0  = LDROW(0),  m1  = LDROW(1),  m2  = LDROW(2),  m3  = LDROW(3);
    u64 m4  = LDROW(4),  m5  = LDROW(5),  m6  = LDROW(6),  m7  = LDROW(7);
    u64 m8  = LDROW(8),  m9  = LDROW(9),  m10 = LDROW(10), m11 = LDROW(11);
    u64 m12 = LDROW(12), m13 = LDROW(13), m14 = LDROW(14), m15 = LDROW(15);

#define STEP(idx, mr) {                                        \
        const int w0 = (idx) >> 6;                             \
        u64 cw = __shfl(supp, w0);                             \
        if (!((cw >> ((idx) & 63)) & 1ull))                    \
            supp |= (lane >= w0) ? mr : 0ull;                  \
        mr = LDROW((idx) + 16); }

    for (int i = 0; i < K; i += 16) {
        STEP(i + 0,  m0);  STEP(i + 1,  m1);  STEP(i + 2,  m2);  STEP(i + 3,  m3);
        STEP(i + 4,  m4);  STEP(i + 5,  m5);  STEP(i + 6,  m6);  STEP(i + 7,  m7);
        STEP(i + 8,  m8);  STEP(i + 9,  m9);  STEP(i + 10, m10); STEP(i + 11, m11);
        STEP(i + 12, m12); STEP(i + 13, m13); STEP(i + 14, m14); STEP(i + 15, m15);
    }
#undef STEP
#undef LDROW

    const size_t base = (size_t)img * TOTK + CAT_OFF[lvl];
    for (int c = 0; c < W; ++c) {
        u64 w = __shfl(supp, c);
        int r = c * 64 + lane;
        if (r < K && ((w >> lane) & 1ull)) scores_ws[base + r] = NEGV;
    }
}

// ---------------------------------------------------------------------------
// Kernel 2 (fallback, ws too small): single-wave greedy NMS (proven correct)
// ---------------------------------------------------------------------------
__global__ __launch_bounds__(64) void nms_kernel(
    const float4* __restrict__ boxes_ws, float* __restrict__ scores_ws)
{
    const int img = blockIdx.x / NLVL;
    const int lvl = blockIdx.x % NLVL;
    const int K   = LVL_K[lvl];
    const size_t base = (size_t)img * TOTK + CAT_OFF[lvl];
    const int lane = threadIdx.x;

    __shared__ float4 bs[MAXK];
    for (int i = lane; i < K; i += 64) bs[i] = boxes_ws[base + i];
    __syncthreads();

    u64 myw = 0ull;
    for (int i = 0; i < K; ++i) {
        u64 wi = __shfl(myw, i >> 6);
        bool suppressed = (wi >> (i & 63)) & 1ull;
        if (!suppressed) {
            float4 bi = bs[i];
            float areaA = (bi.z - bi.x) * (bi.w - bi.y);
            for (int jb = i + 1; jb < K; jb += 64) {
                int j = jb + lane;
                bool over = false;
                if (j < K) over = iou_over(bi, areaA, bs[j]);
                u64 m = __ballot(over);
                int w0 = jb >> 6;
                int sh = jb & 63;
                if (lane == w0) myw |= (m << sh);
                if (sh && lane == (w0 + 1)) myw |= (m >> (64 - sh));
            }
        }
    }
    const int nch = (K + 63) >> 6;
    for (int c = 0; c < nch; ++c) {
        u64 w = __shfl(myw, c);
        int r = c * 64 + lane;
        if (r < K && ((w >> lane) & 1ull)) scores_ws[base + r] = NEGV;
    }
}

// ---------------------------------------------------------------------------
// final_topk: per-image exact top-1000 (proven round-4 code, unchanged)
// ---------------------------------------------------------------------------
__device__ void radix_topk_sorted(const float* __restrict__ s, int n, int k, int P,
                                  u32* hist, u32* chunk, u64* buf, u64* bcast, int* ibcast)
{
    const int tid = threadIdx.x;
    const int wid = tid >> 6;
    u64 pref = 0ull;
    int remk = k;
    int done = 0;
    const int SH[6] = {53, 42, 31, 20, 9, 0};
    const int WD[6] = {11, 11, 11, 11, 11, 9};

    for (int pass = 0; pass < 6 && !done; ++pass) {
        const int shift = SH[pass];
        const int nb    = 1 << WD[pass];
        for (int b = tid; b < 4 * 2048; b += T_BLK) hist[b] = 0u;
        __syncthreads();
        const u64 himask = (pass == 0) ? 0ull : (~0ull << SH[pass - 1]);
        u32* myh = hist + wid * 2048;
        for (int i0 = tid * 4; i0 < n; i0 += T_BLK * 4) {
            float4 v = *(const float4*)(s + i0);
            u64 k0 = make_key(v.x, i0);
            u64 k1 = make_key(v.y, i0 + 1);
            u64 k2 = make_key(v.z, i0 + 2);
            u64 k3 = make_key(v.w, i0 + 3);
            if ((k0 & himask) == pref) atomicAdd(&myh[(u32)(k0 >> shift) & (nb - 1)], 1u);
            if ((k1 & himask) == pref) atomicAdd(&myh[(u32)(k1 >> shift) & (nb - 1)], 1u);
            if ((k2 & himask) == pref) atomicAdd(&myh[(u32)(k2 >> shift) & (nb - 1)], 1u);
            if ((k3 & himask) == pref) atomicAdd(&myh[(u32)(k3 >> shift) & (nb - 1)], 1u);
        }
        __syncthreads();
        u32 csum = 0;
        for (int b = tid * 8; b < tid * 8 + 8; ++b)
            if (b < nb) csum += hist[b] + hist[2048 + b] + hist[4096 + b] + hist[6144 + b];
        chunk[tid] = csum;
        __syncthreads();
        if (tid == 0) {
            int cum = 0, cidx = 0;
            for (int c = 255; c >= 0; --c) {
                int cs = (int)chunk[c];
                if (cum + cs >= remk) { cidx = c; break; }
                cum += cs;
            }
            for (int b = cidx * 8 + 7; b >= cidx * 8; --b) {
                if (b >= nb) continue;
                int cb = (int)(hist[b] + hist[2048 + b] + hist[4096 + b] + hist[6144 + b]);
                if (cum + cb >= remk) {
                    bcast[0]  = pref | (((u64)(u32)b) << shift);
                    ibcast[0] = remk - cum;
                    ibcast[1] = (cb == (remk - cum)) ? 1 : 0;
                    break;
                }
                cum += cb;
            }
        }
        __syncthreads();
        pref = bcast[0];
        remk = ibcast[0];
        done = ibcast[1];
        __syncthreads();
    }
    const u64 thresh = pref;

    if (tid == 0) ibcast[2] = 0;
    __syncthreads();
    for (int i0 = tid * 4; i0 < n; i0 += T_BLK * 4) {
        float4 v = *(const float4*)(s + i0);
        u64 kk[4] = { make_key(v.x, i0), make_key(v.y, i0 + 1),
                      make_key(v.z, i0 + 2), make_key(v.w, i0 + 3) };
        #pragma unroll
        for (int q = 0; q < 4; ++q) {
            if (kk[q] >= thresh) {
                int pos = atomicAdd(&ibcast[2], 1);
                if (pos < P) buf[pos] = kk[q];
            }
        }
    }
    __syncthreads();
    for (int i = k + tid; i < P; i += T_BLK) buf[i] = 0ull;
    __syncthreads();

    for (int sz = 2; sz <= P; sz <<= 1) {
        for (int st = sz >> 1; st > 0; st >>= 1) {
            for (int i = tid; i < P; i += T_BLK) {
                int j = i ^ st;
                if (j > i) {
                    u64 a = buf[i];
                    u64 b = buf[j];
                    bool up = ((i & sz) == 0);
                    if ((a > b) == up) { buf[i] = b; buf[j] = a; }
                }
            }
            __syncthreads();
        }
    }
}

__global__ __launch_bounds__(T_BLK) void final_topk_kernel(
    const float4* __restrict__ boxes_ws, const float* __restrict__ scores_ws,
    float* __restrict__ out)
{
    const int img = blockIdx.x;
    const float* s = scores_ws + (size_t)img * TOTK;

    __shared__ u32 hist[4 * 2048];
    __shared__ u32 chunk[256];
    __shared__ u64 buf[1024];
    __shared__ u64 bcast;
    __shared__ int ibcast[4];

    radix_topk_sorted(s, TOTK, FINAL_K, 1024, hist, chunk, buf, &bcast, ibcast);

    const int tid = threadIdx.x;
    float4* outb = (float4*)out;               // fboxes: [16][1000][4]
    float*  outs = out + NIMG * FINAL_K * 4;   // fscores: [16][1000]
    for (int r = tid; r < FINAL_K; r += T_BLK) {
        u64 kk = buf[1024 - 1 - r];
        int idx = (int)(0xFFFFFFFFu - (unsigned)(kk & 0xFFFFFFFFull));
        outb[img * FINAL_K + r] = boxes_ws[(size_t)img * TOTK + idx];
        outs[img * FINAL_K + r] = s[idx];
    }
}

// ---------------------------------------------------------------------------
extern "C" void kernel_launch(void* const* d_in, const int* in_sizes, int n_in,
                              void* d_out, int out_size, void* d_ws, size_t ws_size,
                              hipStream_t stream)
{
    const float*  obj     = (const float*)d_in[0];
    const float4* deltas  = (const float4*)d_in[1];
    const float4* anchors = (const float4*)d_in[2];
    float* out = (float*)d_out;

    char* ws = (char*)d_ws;
    float4* boxes_ws  = (float4*)(ws + BOX_OFF);
    float*  scores_ws = (float*)(ws + SCORES_OFF);
    u32*    ghist     = (u32*)(ws + GHIST_OFF);
    u32*    cand_cnt  = (u32*)(ws + CNT_OFF);
    u32*    gbound    = (u32*)(ws + GB_OFF);
    u64*    cand      = (u64*)(ws + CAND_OFF);

    zero_kernel<<<512, T_BLK, 0, stream>>>(ghist);   // ghist + cand_cnt contiguous
    hist_kernel<<<NIMG * NSLICE, T_BLK, 0, stream>>>(obj, ghist);
    bound_kernel<<<NIMG * NLVL, T_BLK, 0, stream>>>(ghist, gbound);
    compact_kernel<<<NIMG * NSLICE, T_BLK, 0, stream>>>(obj, gbound, cand_cnt, cand);
    sort_decode_kernel<<<NIMG * NLVL, T_BLK, 0, stream>>>(deltas, anchors, cand_cnt, cand,
                                                          boxes_ws, scores_ws);

    if (ws_size >= MASK_OFF + MASK_BYTES) {
        u64* mask = (u64*)(ws + MASK_OFF);
        nms_mask_kernel<<<NIMG * NLVL * 32, T_BLK, 0, stream>>>(boxes_ws, mask);
        nms_scan_kernel<<<NIMG * NLVL, 64, 0, stream>>>(mask, scores_ws);
    } else {
        nms_kernel<<<NIMG * NLVL, 64, 0, stream>>>(boxes_ws, scores_ws);
    }

    final_topk_kernel<<<NIMG, T_BLK, 0, stream>>>(boxes_ws, scores_ws, out);
}

// Round 6
// 699.115 us; speedup vs baseline: 10.7853x; 1.4292x over previous
//
#include <hip/hip_runtime.h>
#include <stdint.h>

typedef unsigned long long u64;
typedef unsigned u32;

// ---------------------------------------------------------------------------
// RPN proposal generation (decode + per-level topk + NMS + final topk)
// ---------------------------------------------------------------------------

constexpr int NIMG = 16;
constexpr int NLVL = 5;
constexpr int ATOT = 261888;
__device__ constexpr int LVL_N[5]   = {196608, 49152, 12288, 3072, 768};
__device__ constexpr int LVL_OFF[5] = {0, 196608, 245760, 258048, 261120};
__device__ constexpr int LVL_K[5]   = {2000, 2000, 2000, 2000, 768};
__device__ constexpr int CAT_OFF[5] = {0, 2000, 4000, 6000, 8000};
constexpr int TOTK = 8768;          // 4*2000 + 768
constexpr int FINAL_K = 1000;
constexpr float NEGV = -1000000000.0f;
constexpr float CLIPV = 4.135166556742356f;   // log(1000/16)
constexpr float IMGSZ = 1024.0f;
constexpr float NMS_T = 0.7f;
constexpr int MAXK = 2000;
constexpr int MW   = 32;            // mask words per row (ceil(2000/64))
constexpr int MAXT = 528;           // 64x64 tiles per problem (W=32 upper triangle)

constexpr int NSLICE  = 65;         // per image: 48 + 12 + 3 + 1 + 1 (4096-item slices)
constexpr int NBIN    = 8192;       // 13-bit first-digit bins
constexpr int CANDCAP = 4096;       // per-problem candidate capacity

#define T_BLK 256

// ---------------- workspace layout (bytes) ----------------
constexpr size_t BOX_OFF    = 0;                                   // 16*8768*16
constexpr size_t SCORES_OFF = (size_t)NIMG * TOTK * 16;            // 2,244,608
constexpr size_t GHIST_OFF  = SCORES_OFF + (size_t)NIMG * TOTK * 4;// 2,805,760
constexpr size_t CNT_OFF    = GHIST_OFF + (size_t)NIMG * NLVL * NBIN * 4; // 5,427,200
constexpr size_t GB_OFF     = CNT_OFF + (size_t)NIMG * NLVL * 4;   // 5,427,520
constexpr size_t CAND_OFF   = GB_OFF + (size_t)NIMG * NLVL * 4;    // 5,427,840
constexpr size_t MASK_OFF   = ((CAND_OFF + (size_t)NIMG * NLVL * CANDCAP * 8) + 255) & ~(size_t)255;
constexpr size_t MASK_BYTES = (size_t)NIMG * NLVL * MAXK * MW * 8; // ~41 MB
constexpr int    ZERO_WORDS = NIMG * NLVL * NBIN + NIMG * NLVL;    // ghist + cand_cnt (contiguous)

// ordered-uint mapping: monotone with float value
__device__ inline unsigned ordf(float f) {
    unsigned u = __float_as_uint(f);
    return (u & 0x80000000u) ? ~u : (u | 0x80000000u);
}

__device__ inline u64 make_key(float sc, int idx) {
    return (((u64)ordf(sc)) << 32) | (u64)(0xFFFFFFFFu - (unsigned)idx);
}

// decode + clip, faithful to reference float32 op order (no FMA contraction)
__device__ inline float4 decode_clip(const float4 an, const float4 dl) {
#pragma clang fp contract(off)
    float w  = an.z - an.x;
    float h  = an.w - an.y;
    float cx = an.x + 0.5f * w;
    float cy = an.y + 0.5f * h;
    float dw = fminf(dl.z, CLIPV);
    float dh = fminf(dl.w, CLIPV);
    float pcx = dl.x * w + cx;
    float pcy = dl.y * h + cy;
    float pw  = expf(dw) * w;
    float ph  = expf(dh) * h;
    float x1 = pcx - 0.5f * pw;
    float y1 = pcy - 0.5f * ph;
    float x2 = pcx + 0.5f * pw;
    float y2 = pcy + 0.5f * ph;
    x1 = fminf(fmaxf(x1, 0.0f), IMGSZ);
    x2 = fminf(fmaxf(x2, 0.0f), IMGSZ);
    y1 = fminf(fmaxf(y1, 0.0f), IMGSZ);
    y2 = fminf(fmaxf(y2, 0.0f), IMGSZ);
    return make_float4(x1, y1, x2, y2);
}

// IoU > thresh with precomputed areas; bit-identical op order to reference
__device__ inline bool iou_over2(const float4 a, float areaA, const float4 b, float areaB) {
#pragma clang fp contract(off)
    float ltx = fmaxf(a.x, b.x);
    float lty = fmaxf(a.y, b.y);
    float rbx = fminf(a.z, b.z);
    float rby = fminf(a.w, b.w);
    float w = fmaxf(rbx - ltx, 0.0f);
    float h = fmaxf(rby - lty, 0.0f);
    float inter = w * h;
    float iou = inter / (((areaA + areaB) - inter) + 1e-9f);
    return iou > NMS_T;
}

__device__ inline bool iou_over(const float4 a, float areaA, const float4 b) {
    float areaB = (b.z - b.x) * (b.w - b.y);
    return iou_over2(a, areaA, b, areaB);
}

// slice id -> (lvl, offset-in-level, length); uniform per block
__device__ inline void slice_map(int sid, int& lvl, int& loff, int& len) {
    if (sid < 48)      { lvl = 0; loff = sid * 4096;        len = 4096; }
    else if (sid < 60) { lvl = 1; loff = (sid - 48) * 4096; len = 4096; }
    else if (sid < 63) { lvl = 2; loff = (sid - 60) * 4096; len = 4096; }
    else if (sid == 63){ lvl = 3; loff = 0;                 len = 3072; }
    else               { lvl = 4; loff = 0;                 len = 768;  }
}

// ---------------------------------------------------------------------------
// Kernel 0: zero ghist + cand_cnt
// ---------------------------------------------------------------------------
__global__ __launch_bounds__(T_BLK) void zero_kernel(u32* __restrict__ dst) {
    for (int i = blockIdx.x * T_BLK + threadIdx.x; i < ZERO_WORDS; i += gridDim.x * T_BLK)
        dst[i] = 0u;
}

// ---------------------------------------------------------------------------
// Kernel A: distributed 13-bit score histogram per (img,lvl)
// ---------------------------------------------------------------------------
__global__ __launch_bounds__(T_BLK) void hist_kernel(
    const float* __restrict__ obj, u32* __restrict__ ghist)
{
    const int img = blockIdx.x / NSLICE;
    const int sid = blockIdx.x % NSLICE;
    int lvl, loff, len;
    slice_map(sid, lvl, loff, len);
    const int p = img * NLVL + lvl;
    const float* s = obj + (size_t)img * ATOT + LVL_OFF[lvl] + loff;
    const int tid = threadIdx.x;

    __shared__ u32 hist[NBIN];
    for (int b = tid; b < NBIN; b += T_BLK) hist[b] = 0u;
    __syncthreads();

    for (int i0 = tid * 4; i0 < len; i0 += T_BLK * 4) {
        float4 v = *(const float4*)(s + i0);
        atomicAdd(&hist[ordf(v.x) >> 19], 1u);
        atomicAdd(&hist[ordf(v.y) >> 19], 1u);
        atomicAdd(&hist[ordf(v.z) >> 19], 1u);
        atomicAdd(&hist[ordf(v.w) >> 19], 1u);
    }
    __syncthreads();

    u32* gh = ghist + (size_t)p * NBIN;
    for (int b = tid; b < NBIN; b += T_BLK) {
        u32 v = hist[b];
        if (v) atomicAdd(&gh[b], v);
    }
}

// ---------------------------------------------------------------------------
// Kernel B: boundary bin per problem.  b* = max b with count(digit >= b) >= k.
// ---------------------------------------------------------------------------
__global__ __launch_bounds__(T_BLK) void bound_kernel(
    const u32* __restrict__ ghist, u32* __restrict__ gbound)
{
    const int p   = blockIdx.x;
    const int lvl = p % NLVL;
    const u32 k   = (u32)LVL_K[lvl];
    const u32* gh = ghist + (size_t)p * NBIN;
    const int tid = threadIdx.x;

    u32 ch = 0;
    for (int b = tid * 32; b < tid * 32 + 32; ++b) ch += gh[b];

    __shared__ u32 suf[T_BLK];
    suf[tid] = ch;
    __syncthreads();
    for (int d = 1; d < T_BLK; d <<= 1) {
        u32 add = (tid + d < T_BLK) ? suf[tid + d] : 0u;
        __syncthreads();
        suf[tid] += add;
        __syncthreads();
    }
    const u32 inc = suf[tid];                    // count(digit >= tid*32)
    if (inc >= k && inc - ch < k) {              // boundary chunk: exactly one thread
        u32 cum = inc - ch;                      // count above this chunk
        int bin = tid * 32;
        for (int b = tid * 32 + 31; b >= tid * 32; --b) {
            u32 hb = gh[b];
            if (cum + hb >= k) { bin = b; break; }
            cum += hb;
        }
        gbound[p] = (u32)bin;
    }
}

// ---------------------------------------------------------------------------
// Kernel C: compact candidate keys (digit >= boundary bin); wave-aggregated
// atomics (1 atomicAdd per wave instead of per item).
// ---------------------------------------------------------------------------
__global__ __launch_bounds__(T_BLK) void compact_kernel(
    const float* __restrict__ obj, const u32* __restrict__ gbound,
    u32* __restrict__ cand_cnt, u64* __restrict__ cand)
{
    const int img = blockIdx.x / NSLICE;
    const int sid = blockIdx.x % NSLICE;
    int lvl, loff, len;
    slice_map(sid, lvl, loff, len);
    const int p = img * NLVL + lvl;
    const u32 bin = gbound[p];
    const float* s = obj + (size_t)img * ATOT + LVL_OFF[lvl] + loff;
    const int tid  = threadIdx.x;
    const int lane = tid & 63;
    u64* cp = cand + (size_t)p * CANDCAP;

    const u64 below = (lane == 0) ? 0ull : (~0ull >> (64 - lane));

    for (int i0 = tid * 4; i0 < len; i0 += T_BLK * 4) {
        float4 v = *(const float4*)(s + i0);
        float vv[4] = {v.x, v.y, v.z, v.w};
        bool ps[4];
        #pragma unroll
        for (int q = 0; q < 4; ++q) ps[q] = (ordf(vv[q]) >> 19) >= bin;
        u64 b0 = __ballot(ps[0]);
        u64 b1 = __ballot(ps[1]);
        u64 b2 = __ballot(ps[2]);
        u64 b3 = __ballot(ps[3]);
        int c0 = __popcll(b0), c1 = __popcll(b1), c2 = __popcll(b2), c3 = __popcll(b3);
        int tot = c0 + c1 + c2 + c3;
        if (tot == 0) continue;                  // wave-uniform
        u32 base_ = 0;
        if (lane == 0) base_ = atomicAdd(&cand_cnt[p], (u32)tot);
        base_ = (u32)__shfl((int)base_, 0);
        int o0 = (int)base_ + __popcll(b0 & below);
        int o1 = (int)base_ + c0 + __popcll(b1 & below);
        int o2 = (int)base_ + c0 + c1 + __popcll(b2 & below);
        int o3 = (int)base_ + c0 + c1 + c2 + __popcll(b3 & below);
        if (ps[0] && o0 < CANDCAP) cp[o0] = make_key(vv[0], loff + i0 + 0);
        if (ps[1] && o1 < CANDCAP) cp[o1] = make_key(vv[1], loff + i0 + 1);
        if (ps[2] && o2 < CANDCAP) cp[o2] = make_key(vv[2], loff + i0 + 2);
        if (ps[3] && o3 < CANDCAP) cp[o3] = make_key(vv[3], loff + i0 + 3);
    }
}

// ---------------------------------------------------------------------------
// Kernel D: per-problem exact top-k (bitonic over candidates) + decode + clip
// ---------------------------------------------------------------------------
__global__ __launch_bounds__(T_BLK) void sort_decode_kernel(
    const float4* __restrict__ deltas, const float4* __restrict__ anchors,
    const u32* __restrict__ cand_cnt, const u64* __restrict__ cand,
    float4* __restrict__ boxes_ws, float* __restrict__ scores_ws)
{
    const int p   = blockIdx.x;
    const int img = p / NLVL;
    const int lvl = p % NLVL;
    const int k   = LVL_K[lvl];
    const int off = LVL_OFF[lvl];
    const int tid = threadIdx.x;
    const int cnt = min((int)cand_cnt[p], CANDCAP);
    const u64* cp = cand + (size_t)p * CANDCAP;

    __shared__ u64 buf[CANDCAP];
    for (int i = tid; i < CANDCAP; i += T_BLK) buf[i] = (i < cnt) ? cp[i] : 0ull;
    __syncthreads();

    // bitonic sort ascending over CANDCAP elements (keys distinct, 0-padded)
    for (int sz = 2; sz <= CANDCAP; sz <<= 1) {
        for (int st = sz >> 1; st > 0; st >>= 1) {
            for (int i = tid; i < CANDCAP; i += T_BLK) {
                int j = i ^ st;
                if (j > i) {
                    u64 a = buf[i];
                    u64 b = buf[j];
                    bool up = ((i & sz) == 0);
                    if ((a > b) == up) { buf[i] = b; buf[j] = a; }
                }
            }
            __syncthreads();
        }
    }

    const size_t outbase = (size_t)img * TOTK + CAT_OFF[lvl];
    for (int r = tid; r < k; r += T_BLK) {
        u64 kk = buf[CANDCAP - 1 - r];
        int li = (int)(0xFFFFFFFFu - (unsigned)(kk & 0xFFFFFFFFull));
        int g  = off + li;
        u32 hu = (u32)(kk >> 32);                // bit-exact score recovery
        u32 fu = (hu & 0x80000000u) ? (hu ^ 0x80000000u) : ~hu;
        float sc = __uint_as_float(fu);
        float4 an = anchors[g];
        float4 dl = deltas[(size_t)img * ATOT + g];
        boxes_ws[outbase + r]  = decode_clip(an, dl);
        scores_ws[outbase + r] = sc;
    }
}

// ---------------------------------------------------------------------------
// Kernel 2a: pairwise IoU>thresh bitmask, 64x64 tiles (balanced), columns in
// registers, coalesced writes. Mask layout: mask[p][w][i] (word-major),
// word w bit l  <=>  IoU(box_i, box_{w*64+l}) > 0.7, for j > i.
// Block = 256 threads = 4 waves x 16 rows; one block per (rt, ct>=rt) tile.
// ---------------------------------------------------------------------------
__global__ __launch_bounds__(T_BLK) void nms_mask_kernel(
    const float4* __restrict__ boxes_ws, u64* __restrict__ mask)
{
    const int p   = blockIdx.x / MAXT;
    const int t   = blockIdx.x % MAXT;
    const int img = p / NLVL;
    const int lvl = p % NLVL;
    const int K   = LVL_K[lvl];
    const int W   = (K + 63) >> 6;
    const int T   = (W * (W + 1)) >> 1;
    if (t >= T) return;                   // uniform across block

    // triangular decode: tile (rt, ct), ct >= rt
    int rt = 0, acc = 0;
    while (acc + (W - rt) <= t) { acc += (W - rt); ++rt; }
    const int ct = rt + (t - acc);

    const int lane = threadIdx.x & 63;
    const int wv   = threadIdx.x >> 6;
    const size_t base = (size_t)img * TOTK + CAT_OFF[lvl];

    __shared__ float4 rowb[64];
    __shared__ u64    om[64];

    if (threadIdx.x < 64) {
        int i = rt * 64 + threadIdx.x;
        rowb[threadIdx.x] = (i < K) ? boxes_ws[base + i] : make_float4(0.f, 0.f, 0.f, 0.f);
    }
    __syncthreads();

    const int j = ct * 64 + lane;
    const bool jv = (j < K);
    const float4 bj = jv ? boxes_ws[base + j] : make_float4(0.f, 0.f, 0.f, 0.f);
    const float areaB = (bj.z - bj.x) * (bj.w - bj.y);

    #pragma unroll 4
    for (int r = 0; r < 16; ++r) {
        const int ri = wv * 16 + r;
        const int i  = rt * 64 + ri;
        if (i >= K) break;                // wave-uniform
        const float4 bi = rowb[ri];
        const float areaA = (bi.z - bi.x) * (bi.w - bi.y);
        bool over = jv & (j > i) & iou_over2(bi, areaA, bj, areaB);
        u64 m = __ballot(over);
        if (lane == 0) om[ri] = m;
    }
    __syncthreads();

    if (threadIdx.x < 64) {
        int i = rt * 64 + threadIdx.x;
        if (i < K)
            mask[(size_t)p * MW * MAXK + (size_t)ct * MAXK + i] = om[threadIdx.x];
    }
}

// ---------------------------------------------------------------------------
// Kernel 2b: serial greedy scan over precomputed mask. One wave per problem.
// Word-major layout: lane l streams mask[p][l][i] unit-stride over i.
// ---------------------------------------------------------------------------
__global__ __launch_bounds__(64) void nms_scan_kernel(
    const u64* __restrict__ mask, float* __restrict__ scores_ws)
{
    const int p   = blockIdx.x;
    const int img = p / NLVL;
    const int lvl = p % NLVL;
    const int K   = LVL_K[lvl];
    const int W   = (K + 63) >> 6;
    const int lane = threadIdx.x;
    const u64* rowp = mask + (size_t)p * MW * MAXK + (size_t)lane * MAXK;

    u64 supp = 0ull;

#define LDROW(i) ((lane < MW) ? rowp[(((i) < K) ? (i) : (K - 1))] : 0ull)
    u64 m0  = LDROW(0),  m1  = LDROW(1),  m2  = LDROW(2),  m3  = LDROW(3);
    u64 m4  = LDROW(4),  m5  = LDROW(5),  m6  = LDROW(6),  m7  = LDROW(7);
    u64 m8  = LDROW(8),  m9  = LDROW(9),  m10 = LDROW(10), m11 = LDROW(11);
    u64 m12 = LDROW(12), m13 = LDROW(13), m14 = LDROW(14), m15 = LDROW(15);

#define STEP(idx, mr) {                                        \
        const int w0 = (idx) >> 6;                             \
        u64 cw = __shfl(supp, w0);                             \
        if (!((cw >> ((idx) & 63)) & 1ull))                    \
            supp |= (lane >= w0) ? mr : 0ull;                  \
        mr = LDROW((idx) + 16); }

    for (int i = 0; i < K; i += 16) {
        STEP(i + 0,  m0);  STEP(i + 1,  m1);  STEP(i + 2,  m2);  STEP(i + 3,  m3);
        STEP(i + 4,  m4);  STEP(i + 5,  m5);  STEP(i + 6,  m6);  STEP(i + 7,  m7);
        STEP(i + 8,  m8);  STEP(i + 9,  m9);  STEP(i + 10, m10); STEP(i + 11, m11);
        STEP(i + 12, m12); STEP(i + 13, m13); STEP(i + 14, m14); STEP(i + 15, m15);
    }
#undef STEP
#undef LDROW

    const size_t base = (size_t)img * TOTK + CAT_OFF[lvl];
    for (int c = 0; c < W; ++c) {
        u64 w = __shfl(supp, c);
        int r = c * 64 + lane;
        if (r < K && ((w >> lane) & 1ull)) scores_ws[base + r] = NEGV;
    }
}

// ---------------------------------------------------------------------------
// Kernel 2 (fallback, ws too small): single-wave greedy NMS (proven correct)
// ---------------------------------------------------------------------------
__global__ __launch_bounds__(64) void nms_kernel(
    const float4* __restrict__ boxes_ws, float* __restrict__ scores_ws)
{
    const int img = blockIdx.x / NLVL;
    const int lvl = blockIdx.x % NLVL;
    const int K   = LVL_K[lvl];
    const size_t base = (size_t)img * TOTK + CAT_OFF[lvl];
    const int lane = threadIdx.x;

    __shared__ float4 bs[MAXK];
    for (int i = lane; i < K; i += 64) bs[i] = boxes_ws[base + i];
    __syncthreads();

    u64 myw = 0ull;
    for (int i = 0; i < K; ++i) {
        u64 wi = __shfl(myw, i >> 6);
        bool suppressed = (wi >> (i & 63)) & 1ull;
        if (!suppressed) {
            float4 bi = bs[i];
            float areaA = (bi.z - bi.x) * (bi.w - bi.y);
            for (int jb = i + 1; jb < K; jb += 64) {
                int j = jb + lane;
                bool over = false;
                if (j < K) over = iou_over(bi, areaA, bs[j]);
                u64 m = __ballot(over);
                int w0 = jb >> 6;
                int sh = jb & 63;
                if (lane == w0) myw |= (m << sh);
                if (sh && lane == (w0 + 1)) myw |= (m >> (64 - sh));
            }
        }
    }
    const int nch = (K + 63) >> 6;
    for (int c = 0; c < nch; ++c) {
        u64 w = __shfl(myw, c);
        int r = c * 64 + lane;
        if (r < K && ((w >> lane) & 1ull)) scores_ws[base + r] = NEGV;
    }
}

// ---------------------------------------------------------------------------
// final_topk: per-image exact top-1000 (proven code, unchanged)
// ---------------------------------------------------------------------------
__device__ void radix_topk_sorted(const float* __restrict__ s, int n, int k, int P,
                                  u32* hist, u32* chunk, u64* buf, u64* bcast, int* ibcast)
{
    const int tid = threadIdx.x;
    const int wid = tid >> 6;
    u64 pref = 0ull;
    int remk = k;
    int done = 0;
    const int SH[6] = {53, 42, 31, 20, 9, 0};
    const int WD[6] = {11, 11, 11, 11, 11, 9};

    for (int pass = 0; pass < 6 && !done; ++pass) {
        const int shift = SH[pass];
        const int nb    = 1 << WD[pass];
        for (int b = tid; b < 4 * 2048; b += T_BLK) hist[b] = 0u;
        __syncthreads();
        const u64 himask = (pass == 0) ? 0ull : (~0ull << SH[pass - 1]);
        u32* myh = hist + wid * 2048;
        for (int i0 = tid * 4; i0 < n; i0 += T_BLK * 4) {
            float4 v = *(const float4*)(s + i0);
            u64 k0 = make_key(v.x, i0);
            u64 k1 = make_key(v.y, i0 + 1);
            u64 k2 = make_key(v.z, i0 + 2);
            u64 k3 = make_key(v.w, i0 + 3);
            if ((k0 & himask) == pref) atomicAdd(&myh[(u32)(k0 >> shift) & (nb - 1)], 1u);
            if ((k1 & himask) == pref) atomicAdd(&myh[(u32)(k1 >> shift) & (nb - 1)], 1u);
            if ((k2 & himask) == pref) atomicAdd(&myh[(u32)(k2 >> shift) & (nb - 1)], 1u);
            if ((k3 & himask) == pref) atomicAdd(&myh[(u32)(k3 >> shift) & (nb - 1)], 1u);
        }
        __syncthreads();
        u32 csum = 0;
        for (int b = tid * 8; b < tid * 8 + 8; ++b)
            if (b < nb) csum += hist[b] + hist[2048 + b] + hist[4096 + b] + hist[6144 + b];
        chunk[tid] = csum;
        __syncthreads();
        if (tid == 0) {
            int cum = 0, cidx = 0;
            for (int c = 255; c >= 0; --c) {
                int cs = (int)chunk[c];
                if (cum + cs >= remk) { cidx = c; break; }
                cum += cs;
            }
            for (int b = cidx * 8 + 7; b >= cidx * 8; --b) {
                if (b >= nb) continue;
                int cb = (int)(hist[b] + hist[2048 + b] + hist[4096 + b] + hist[6144 + b]);
                if (cum + cb >= remk) {
                    bcast[0]  = pref | (((u64)(u32)b) << shift);
                    ibcast[0] = remk - cum;
                    ibcast[1] = (cb == (remk - cum)) ? 1 : 0;
                    break;
                }
                cum += cb;
            }
        }
        __syncthreads();
        pref = bcast[0];
        remk = ibcast[0];
        done = ibcast[1];
        __syncthreads();
    }
    const u64 thresh = pref;

    if (tid == 0) ibcast[2] = 0;
    __syncthreads();
    for (int i0 = tid * 4; i0 < n; i0 += T_BLK * 4) {
        float4 v = *(const float4*)(s + i0);
        u64 kk[4] = { make_key(v.x, i0), make_key(v.y, i0 + 1),
                      make_key(v.z, i0 + 2), make_key(v.w, i0 + 3) };
        #pragma unroll
        for (int q = 0; q < 4; ++q) {
            if (kk[q] >= thresh) {
                int pos = atomicAdd(&ibcast[2], 1);
                if (pos < P) buf[pos] = kk[q];
            }
        }
    }
    __syncthreads();
    for (int i = k + tid; i < P; i += T_BLK) buf[i] = 0ull;
    __syncthreads();

    for (int sz = 2; sz <= P; sz <<= 1) {
        for (int st = sz >> 1; st > 0; st >>= 1) {
            for (int i = tid; i < P; i += T_BLK) {
                int j = i ^ st;
                if (j > i) {
                    u64 a = buf[i];
                    u64 b = buf[j];
                    bool up = ((i & sz) == 0);
                    if ((a > b) == up) { buf[i] = b; buf[j] = a; }
                }
            }
            __syncthreads();
        }
    }
}

__global__ __launch_bounds__(T_BLK) void final_topk_kernel(
    const float4* __restrict__ boxes_ws, const float* __restrict__ scores_ws,
    float* __restrict__ out)
{
    const int img = blockIdx.x;
    const float* s = scores_ws + (size_t)img * TOTK;

    __shared__ u32 hist[4 * 2048];
    __shared__ u32 chunk[256];
    __shared__ u64 buf[1024];
    __shared__ u64 bcast;
    __shared__ int ibcast[4];

    radix_topk_sorted(s, TOTK, FINAL_K, 1024, hist, chunk, buf, &bcast, ibcast);

    const int tid = threadIdx.x;
    float4* outb = (float4*)out;               // fboxes: [16][1000][4]
    float*  outs = out + NIMG * FINAL_K * 4;   // fscores: [16][1000]
    for (int r = tid; r < FINAL_K; r += T_BLK) {
        u64 kk = buf[1024 - 1 - r];
        int idx = (int)(0xFFFFFFFFu - (unsigned)(kk & 0xFFFFFFFFull));
        outb[img * FINAL_K + r] = boxes_ws[(size_t)img * TOTK + idx];
        outs[img * FINAL_K + r] = s[idx];
    }
}

// ---------------------------------------------------------------------------
extern "C" void kernel_launch(void* const* d_in, const int* in_sizes, int n_in,
                              void* d_out, int out_size, void* d_ws, size_t ws_size,
                              hipStream_t stream)
{
    const float*  obj     = (const float*)d_in[0];
    const float4* deltas  = (const float4*)d_in[1];
    const float4* anchors = (const float4*)d_in[2];
    float* out = (float*)d_out;

    char* ws = (char*)d_ws;
    float4* boxes_ws  = (float4*)(ws + BOX_OFF);
    float*  scores_ws = (float*)(ws + SCORES_OFF);
    u32*    ghist     = (u32*)(ws + GHIST_OFF);
    u32*    cand_cnt  = (u32*)(ws + CNT_OFF);
    u32*    gbound    = (u32*)(ws + GB_OFF);
    u64*    cand      = (u64*)(ws + CAND_OFF);

    zero_kernel<<<512, T_BLK, 0, stream>>>(ghist);   // ghist + cand_cnt contiguous
    hist_kernel<<<NIMG * NSLICE, T_BLK, 0, stream>>>(obj, ghist);
    bound_kernel<<<NIMG * NLVL, T_BLK, 0, stream>>>(ghist, gbound);
    compact_kernel<<<NIMG * NSLICE, T_BLK, 0, stream>>>(obj, gbound, cand_cnt, cand);
    sort_decode_kernel<<<NIMG * NLVL, T_BLK, 0, stream>>>(deltas, anchors, cand_cnt, cand,
                                                          boxes_ws, scores_ws);

    if (ws_size >= MASK_OFF + MASK_BYTES) {
        u64* mask = (u64*)(ws + MASK_OFF);
        nms_mask_kernel<<<NIMG * NLVL * MAXT, T_BLK, 0, stream>>>(boxes_ws, mask);
        nms_scan_kernel<<<NIMG * NLVL, 64, 0, stream>>>(mask, scores_ws);
    } else {
        nms_kernel<<<NIMG * NLVL, 64, 0, stream>>>(boxes_ws, scores_ws);
    }

    final_topk_kernel<<<NIMG, T_BLK, 0, stream>>>(boxes_ws, scores_ws, out);
}

// Round 7
// 664.276 us; speedup vs baseline: 11.3509x; 1.0524x over previous
//
#include <hip/hip_runtime.h>
#include <stdint.h>

typedef unsigned long long u64;
typedef unsigned u32;

// ---------------------------------------------------------------------------
// RPN proposal generation (decode + per-level topk + NMS + final topk)
// ---------------------------------------------------------------------------

constexpr int NIMG = 16;
constexpr int NLVL = 5;
constexpr int ATOT = 261888;
__device__ constexpr int LVL_N[5]   = {196608, 49152, 12288, 3072, 768};
__device__ constexpr int LVL_OFF[5] = {0, 196608, 245760, 258048, 261120};
__device__ constexpr int LVL_K[5]   = {2000, 2000, 2000, 2000, 768};
__device__ constexpr int CAT_OFF[5] = {0, 2000, 4000, 6000, 8000};
constexpr int TOTK = 8768;          // 4*2000 + 768
constexpr int FINAL_K = 1000;
constexpr float NEGV = -1000000000.0f;
constexpr float CLIPV = 4.135166556742356f;   // log(1000/16)
constexpr float IMGSZ = 1024.0f;
constexpr float NMS_T = 0.7f;
constexpr int MAXK = 2000;
constexpr int MW   = 32;            // mask words per row (ceil(2000/64))
constexpr int MAXT = 528;           // 64x64 tiles per problem (W=32 upper triangle)

constexpr int NSLICE  = 65;         // per image: 48 + 12 + 3 + 1 + 1 (4096-item slices)
constexpr int NBIN    = 8192;       // 13-bit first-digit bins
constexpr int CANDCAP = 4096;       // per-problem candidate capacity

#define T_BLK 256

// ---------------- workspace layout (bytes) ----------------
constexpr size_t BOX_OFF    = 0;                                   // 16*8768*16
constexpr size_t SCORES_OFF = (size_t)NIMG * TOTK * 16;            // 2,244,608
constexpr size_t GHIST_OFF  = SCORES_OFF + (size_t)NIMG * TOTK * 4;// 2,805,760
constexpr size_t CNT_OFF    = GHIST_OFF + (size_t)NIMG * NLVL * NBIN * 4; // 5,427,200
constexpr size_t GB_OFF     = CNT_OFF + (size_t)NIMG * NLVL * 4;   // 5,427,520
constexpr size_t CAND_OFF   = GB_OFF + (size_t)NIMG * NLVL * 4;    // 5,427,840
constexpr size_t MASK_OFF   = ((CAND_OFF + (size_t)NIMG * NLVL * CANDCAP * 8) + 255) & ~(size_t)255;
constexpr size_t MASK_BYTES = (size_t)NIMG * NLVL * MAXK * MW * 8; // ~41 MB
constexpr int    ZERO_WORDS = NIMG * NLVL * NBIN + NIMG * NLVL;    // ghist + cand_cnt (contiguous)

// ordered-uint mapping: monotone with float value
__device__ inline unsigned ordf(float f) {
    unsigned u = __float_as_uint(f);
    return (u & 0x80000000u) ? ~u : (u | 0x80000000u);
}

__device__ inline u64 make_key(float sc, int idx) {
    return (((u64)ordf(sc)) << 32) | (u64)(0xFFFFFFFFu - (unsigned)idx);
}

// decode + clip, faithful to reference float32 op order (no FMA contraction)
__device__ inline float4 decode_clip(const float4 an, const float4 dl) {
#pragma clang fp contract(off)
    float w  = an.z - an.x;
    float h  = an.w - an.y;
    float cx = an.x + 0.5f * w;
    float cy = an.y + 0.5f * h;
    float dw = fminf(dl.z, CLIPV);
    float dh = fminf(dl.w, CLIPV);
    float pcx = dl.x * w + cx;
    float pcy = dl.y * h + cy;
    float pw  = expf(dw) * w;
    float ph  = expf(dh) * h;
    float x1 = pcx - 0.5f * pw;
    float y1 = pcy - 0.5f * ph;
    float x2 = pcx + 0.5f * pw;
    float y2 = pcy + 0.5f * ph;
    x1 = fminf(fmaxf(x1, 0.0f), IMGSZ);
    x2 = fminf(fmaxf(x2, 0.0f), IMGSZ);
    y1 = fminf(fmaxf(y1, 0.0f), IMGSZ);
    y2 = fminf(fmaxf(y2, 0.0f), IMGSZ);
    return make_float4(x1, y1, x2, y2);
}

// IoU > thresh with precomputed areas; bit-identical op order to reference
__device__ inline bool iou_over2(const float4 a, float areaA, const float4 b, float areaB) {
#pragma clang fp contract(off)
    float ltx = fmaxf(a.x, b.x);
    float lty = fmaxf(a.y, b.y);
    float rbx = fminf(a.z, b.z);
    float rby = fminf(a.w, b.w);
    float w = fmaxf(rbx - ltx, 0.0f);
    float h = fmaxf(rby - lty, 0.0f);
    float inter = w * h;
    float iou = inter / (((areaA + areaB) - inter) + 1e-9f);
    return iou > NMS_T;
}

__device__ inline bool iou_over(const float4 a, float areaA, const float4 b) {
    float areaB = (b.z - b.x) * (b.w - b.y);
    return iou_over2(a, areaA, b, areaB);
}

// slice id -> (lvl, offset-in-level, length); uniform per block
__device__ inline void slice_map(int sid, int& lvl, int& loff, int& len) {
    if (sid < 48)      { lvl = 0; loff = sid * 4096;        len = 4096; }
    else if (sid < 60) { lvl = 1; loff = (sid - 48) * 4096; len = 4096; }
    else if (sid < 63) { lvl = 2; loff = (sid - 60) * 4096; len = 4096; }
    else if (sid == 63){ lvl = 3; loff = 0;                 len = 3072; }
    else               { lvl = 4; loff = 0;                 len = 768;  }
}

// ---------------------------------------------------------------------------
// Kernel 0: zero ghist + cand_cnt
// ---------------------------------------------------------------------------
__global__ __launch_bounds__(T_BLK) void zero_kernel(u32* __restrict__ dst) {
    for (int i = blockIdx.x * T_BLK + threadIdx.x; i < ZERO_WORDS; i += gridDim.x * T_BLK)
        dst[i] = 0u;
}

// ---------------------------------------------------------------------------
// Kernel A: distributed 13-bit score histogram per (img,lvl)
// ---------------------------------------------------------------------------
__global__ __launch_bounds__(T_BLK) void hist_kernel(
    const float* __restrict__ obj, u32* __restrict__ ghist)
{
    const int img = blockIdx.x / NSLICE;
    const int sid = blockIdx.x % NSLICE;
    int lvl, loff, len;
    slice_map(sid, lvl, loff, len);
    const int p = img * NLVL + lvl;
    const float* s = obj + (size_t)img * ATOT + LVL_OFF[lvl] + loff;
    const int tid = threadIdx.x;

    __shared__ u32 hist[NBIN];
    for (int b = tid; b < NBIN; b += T_BLK) hist[b] = 0u;
    __syncthreads();

    for (int i0 = tid * 4; i0 < len; i0 += T_BLK * 4) {
        float4 v = *(const float4*)(s + i0);
        atomicAdd(&hist[ordf(v.x) >> 19], 1u);
        atomicAdd(&hist[ordf(v.y) >> 19], 1u);
        atomicAdd(&hist[ordf(v.z) >> 19], 1u);
        atomicAdd(&hist[ordf(v.w) >> 19], 1u);
    }
    __syncthreads();

    u32* gh = ghist + (size_t)p * NBIN;
    for (int b = tid; b < NBIN; b += T_BLK) {
        u32 v = hist[b];
        if (v) atomicAdd(&gh[b], v);
    }
}

// ---------------------------------------------------------------------------
// Kernel B: boundary bin per problem.  b* = max b with count(digit >= b) >= k.
// ---------------------------------------------------------------------------
__global__ __launch_bounds__(T_BLK) void bound_kernel(
    const u32* __restrict__ ghist, u32* __restrict__ gbound)
{
    const int p   = blockIdx.x;
    const int lvl = p % NLVL;
    const u32 k   = (u32)LVL_K[lvl];
    const u32* gh = ghist + (size_t)p * NBIN;
    const int tid = threadIdx.x;

    u32 ch = 0;
    for (int b = tid * 32; b < tid * 32 + 32; ++b) ch += gh[b];

    __shared__ u32 suf[T_BLK];
    suf[tid] = ch;
    __syncthreads();
    for (int d = 1; d < T_BLK; d <<= 1) {
        u32 add = (tid + d < T_BLK) ? suf[tid + d] : 0u;
        __syncthreads();
        suf[tid] += add;
        __syncthreads();
    }
    const u32 inc = suf[tid];                    // count(digit >= tid*32)
    if (inc >= k && inc - ch < k) {              // boundary chunk: exactly one thread
        u32 cum = inc - ch;                      // count above this chunk
        int bin = tid * 32;
        for (int b = tid * 32 + 31; b >= tid * 32; --b) {
            u32 hb = gh[b];
            if (cum + hb >= k) { bin = b; break; }
            cum += hb;
        }
        gbound[p] = (u32)bin;
    }
}

// ---------------------------------------------------------------------------
// Kernel C: compact candidate keys (digit >= boundary bin); wave-aggregated
// atomics (1 atomicAdd per wave instead of per item).
// ---------------------------------------------------------------------------
__global__ __launch_bounds__(T_BLK) void compact_kernel(
    const float* __restrict__ obj, const u32* __restrict__ gbound,
    u32* __restrict__ cand_cnt, u64* __restrict__ cand)
{
    const int img = blockIdx.x / NSLICE;
    const int sid = blockIdx.x % NSLICE;
    int lvl, loff, len;
    slice_map(sid, lvl, loff, len);
    const int p = img * NLVL + lvl;
    const u32 bin = gbound[p];
    const float* s = obj + (size_t)img * ATOT + LVL_OFF[lvl] + loff;
    const int tid  = threadIdx.x;
    const int lane = tid & 63;
    u64* cp = cand + (size_t)p * CANDCAP;

    const u64 below = (lane == 0) ? 0ull : (~0ull >> (64 - lane));

    for (int i0 = tid * 4; i0 < len; i0 += T_BLK * 4) {
        float4 v = *(const float4*)(s + i0);
        float vv[4] = {v.x, v.y, v.z, v.w};
        bool ps[4];
        #pragma unroll
        for (int q = 0; q < 4; ++q) ps[q] = (ordf(vv[q]) >> 19) >= bin;
        u64 b0 = __ballot(ps[0]);
        u64 b1 = __ballot(ps[1]);
        u64 b2 = __ballot(ps[2]);
        u64 b3 = __ballot(ps[3]);
        int c0 = __popcll(b0), c1 = __popcll(b1), c2 = __popcll(b2), c3 = __popcll(b3);
        int tot = c0 + c1 + c2 + c3;
        if (tot == 0) continue;                  // wave-uniform
        u32 base_ = 0;
        if (lane == 0) base_ = atomicAdd(&cand_cnt[p], (u32)tot);
        base_ = (u32)__shfl((int)base_, 0);
        int o0 = (int)base_ + __popcll(b0 & below);
        int o1 = (int)base_ + c0 + __popcll(b1 & below);
        int o2 = (int)base_ + c0 + c1 + __popcll(b2 & below);
        int o3 = (int)base_ + c0 + c1 + c2 + __popcll(b3 & below);
        if (ps[0] && o0 < CANDCAP) cp[o0] = make_key(vv[0], loff + i0 + 0);
        if (ps[1] && o1 < CANDCAP) cp[o1] = make_key(vv[1], loff + i0 + 1);
        if (ps[2] && o2 < CANDCAP) cp[o2] = make_key(vv[2], loff + i0 + 2);
        if (ps[3] && o3 < CANDCAP) cp[o3] = make_key(vv[3], loff + i0 + 3);
    }
}

// ---------------------------------------------------------------------------
// Kernel D: per-problem exact top-k (bitonic over candidates) + decode + clip
// ---------------------------------------------------------------------------
__global__ __launch_bounds__(T_BLK) void sort_decode_kernel(
    const float4* __restrict__ deltas, const float4* __restrict__ anchors,
    const u32* __restrict__ cand_cnt, const u64* __restrict__ cand,
    float4* __restrict__ boxes_ws, float* __restrict__ scores_ws)
{
    const int p   = blockIdx.x;
    const int img = p / NLVL;
    const int lvl = p % NLVL;
    const int k   = LVL_K[lvl];
    const int off = LVL_OFF[lvl];
    const int tid = threadIdx.x;
    const int cnt = min((int)cand_cnt[p], CANDCAP);
    const u64* cp = cand + (size_t)p * CANDCAP;

    __shared__ u64 buf[CANDCAP];
    for (int i = tid; i < CANDCAP; i += T_BLK) buf[i] = (i < cnt) ? cp[i] : 0ull;
    __syncthreads();

    // bitonic sort ascending over CANDCAP elements (keys distinct, 0-padded)
    for (int sz = 2; sz <= CANDCAP; sz <<= 1) {
        for (int st = sz >> 1; st > 0; st >>= 1) {
            for (int i = tid; i < CANDCAP; i += T_BLK) {
                int j = i ^ st;
                if (j > i) {
                    u64 a = buf[i];
                    u64 b = buf[j];
                    bool up = ((i & sz) == 0);
                    if ((a > b) == up) { buf[i] = b; buf[j] = a; }
                }
            }
            __syncthreads();
        }
    }

    const size_t outbase = (size_t)img * TOTK + CAT_OFF[lvl];
    for (int r = tid; r < k; r += T_BLK) {
        u64 kk = buf[CANDCAP - 1 - r];
        int li = (int)(0xFFFFFFFFu - (unsigned)(kk & 0xFFFFFFFFull));
        int g  = off + li;
        u32 hu = (u32)(kk >> 32);                // bit-exact score recovery
        u32 fu = (hu & 0x80000000u) ? (hu ^ 0x80000000u) : ~hu;
        float sc = __uint_as_float(fu);
        float4 an = anchors[g];
        float4 dl = deltas[(size_t)img * ATOT + g];
        boxes_ws[outbase + r]  = decode_clip(an, dl);
        scores_ws[outbase + r] = sc;
    }
}

// ---------------------------------------------------------------------------
// Kernel 2a: pairwise IoU>thresh bitmask, 64x64 tiles (balanced), columns in
// registers, coalesced writes. Mask layout: mask[p][w][i] (word-major),
// word w bit l  <=>  IoU(box_i, box_{w*64+l}) > 0.7, for j > i.
// Block = 256 threads = 4 waves x 16 rows; one block per (rt, ct>=rt) tile.
// ---------------------------------------------------------------------------
__global__ __launch_bounds__(T_BLK) void nms_mask_kernel(
    const float4* __restrict__ boxes_ws, u64* __restrict__ mask)
{
    const int p   = blockIdx.x / MAXT;
    const int t   = blockIdx.x % MAXT;
    const int img = p / NLVL;
    const int lvl = p % NLVL;
    const int K   = LVL_K[lvl];
    const int W   = (K + 63) >> 6;
    const int T   = (W * (W + 1)) >> 1;
    if (t >= T) return;                   // uniform across block

    // triangular decode: tile (rt, ct), ct >= rt
    int rt = 0, acc = 0;
    while (acc + (W - rt) <= t) { acc += (W - rt); ++rt; }
    const int ct = rt + (t - acc);

    const int lane = threadIdx.x & 63;
    const int wv   = threadIdx.x >> 6;
    const size_t base = (size_t)img * TOTK + CAT_OFF[lvl];

    __shared__ float4 rowb[64];
    __shared__ u64    om[64];

    if (threadIdx.x < 64) {
        int i = rt * 64 + threadIdx.x;
        rowb[threadIdx.x] = (i < K) ? boxes_ws[base + i] : make_float4(0.f, 0.f, 0.f, 0.f);
    }
    __syncthreads();

    const int j = ct * 64 + lane;
    const bool jv = (j < K);
    const float4 bj = jv ? boxes_ws[base + j] : make_float4(0.f, 0.f, 0.f, 0.f);
    const float areaB = (bj.z - bj.x) * (bj.w - bj.y);

    #pragma unroll 4
    for (int r = 0; r < 16; ++r) {
        const int ri = wv * 16 + r;
        const int i  = rt * 64 + ri;
        if (i >= K) break;                // wave-uniform
        const float4 bi = rowb[ri];
        const float areaA = (bi.z - bi.x) * (bi.w - bi.y);
        bool over = jv & (j > i) & iou_over2(bi, areaA, bj, areaB);
        u64 m = __ballot(over);
        if (lane == 0) om[ri] = m;
    }
    __syncthreads();

    if (threadIdx.x < 64) {
        int i = rt * 64 + threadIdx.x;
        if (i < K)
            mask[(size_t)p * MW * MAXK + (size_t)ct * MAXK + i] = om[threadIdx.x];
    }
}

// ---------------------------------------------------------------------------
// Kernel 2b: serial greedy scan over precomputed mask. One wave per problem.
// Word-major layout: lane l streams mask[p][l][i] unit-stride over i.
// Suppression state: lane l (<32) owns word l as two u32 halves (slo, shi).
// Bit test for row i uses v_readlane (uniform lane index) -- no LDS shfl in
// the serial chain. 32-deep register prefetch in two 16-row banks.
// ---------------------------------------------------------------------------
__global__ __launch_bounds__(64) void nms_scan_kernel(
    const u64* __restrict__ mask, float* __restrict__ scores_ws)
{
    const int p   = blockIdx.x;
    const int img = p / NLVL;
    const int lvl = p % NLVL;
    const int K   = LVL_K[lvl];
    const int W   = (K + 63) >> 6;
    const int lane = threadIdx.x;
    const u64* rowp = mask + (size_t)p * MW * MAXK + (size_t)lane * MAXK;

    u32 slo = 0u, shi = 0u;   // lane l: suppression bits [64l,64l+32) / [64l+32,64l+64)

#define LDROW(i) ((lane < MW) ? rowp[(((i) < K) ? (i) : (K - 1))] : 0ull)
    u64 a0  = LDROW(0),  a1  = LDROW(1),  a2  = LDROW(2),  a3  = LDROW(3);
    u64 a4  = LDROW(4),  a5  = LDROW(5),  a6  = LDROW(6),  a7  = LDROW(7);
    u64 a8  = LDROW(8),  a9  = LDROW(9),  a10 = LDROW(10), a11 = LDROW(11);
    u64 a12 = LDROW(12), a13 = LDROW(13), a14 = LDROW(14), a15 = LDROW(15);
    u64 b0  = LDROW(16), b1  = LDROW(17), b2  = LDROW(18), b3  = LDROW(19);
    u64 b4  = LDROW(20), b5  = LDROW(21), b6  = LDROW(22), b7  = LDROW(23);
    u64 b8  = LDROW(24), b9  = LDROW(25), b10 = LDROW(26), b11 = LDROW(27);
    u64 b12 = LDROW(28), b13 = LDROW(29), b14 = LDROW(30), b15 = LDROW(31);

#define STEP(idx, mr) {                                                      \
        const int w0_ = (idx) >> 6;                                          \
        u32 clo_ = (u32)__builtin_amdgcn_readlane((int)slo, w0_);            \
        u32 chi_ = (u32)__builtin_amdgcn_readlane((int)shi, w0_);            \
        u64 cw_  = (((u64)chi_) << 32) | (u64)clo_;                          \
        if (!((cw_ >> ((idx) & 63)) & 1ull)) {                               \
            u64 mm_ = (lane >= w0_) ? mr : 0ull;                             \
            slo |= (u32)mm_;                                                 \
            shi |= (u32)(mm_ >> 32);                                         \
        }                                                                    \
        mr = LDROW((idx) + 32); }

    const int nfull = K & ~31;           // 1984 for K=2000, 768 for K=768
    int i = 0;
    for (; i < nfull; i += 32) {
        STEP(i + 0,  a0);  STEP(i + 1,  a1);  STEP(i + 2,  a2);  STEP(i + 3,  a3);
        STEP(i + 4,  a4);  STEP(i + 5,  a5);  STEP(i + 6,  a6);  STEP(i + 7,  a7);
        STEP(i + 8,  a8);  STEP(i + 9,  a9);  STEP(i + 10, a10); STEP(i + 11, a11);
        STEP(i + 12, a12); STEP(i + 13, a13); STEP(i + 14, a14); STEP(i + 15, a15);
        STEP(i + 16, b0);  STEP(i + 17, b1);  STEP(i + 18, b2);  STEP(i + 19, b3);
        STEP(i + 20, b4);  STEP(i + 21, b5);  STEP(i + 22, b6);  STEP(i + 23, b7);
        STEP(i + 24, b8);  STEP(i + 25, b9);  STEP(i + 26, b10); STEP(i + 27, b11);
        STEP(i + 28, b12); STEP(i + 29, b13); STEP(i + 30, b14); STEP(i + 31, b15);
    }
    if (i < K) {                          // 16-row tail (K=2000)
        STEP(i + 0,  a0);  STEP(i + 1,  a1);  STEP(i + 2,  a2);  STEP(i + 3,  a3);
        STEP(i + 4,  a4);  STEP(i + 5,  a5);  STEP(i + 6,  a6);  STEP(i + 7,  a7);
        STEP(i + 8,  a8);  STEP(i + 9,  a9);  STEP(i + 10, a10); STEP(i + 11, a11);
        STEP(i + 12, a12); STEP(i + 13, a13); STEP(i + 14, a14); STEP(i + 15, a15);
    }
#undef STEP
#undef LDROW

    const size_t base = (size_t)img * TOTK + CAT_OFF[lvl];
    for (int c = 0; c < W; ++c) {
        u32 wlo = (u32)__shfl((int)slo, c);
        u32 whi = (u32)__shfl((int)shi, c);
        u64 w = (((u64)whi) << 32) | (u64)wlo;
        int r = c * 64 + lane;
        if (r < K && ((w >> lane) & 1ull)) scores_ws[base + r] = NEGV;
    }
}

// ---------------------------------------------------------------------------
// Kernel 2 (fallback, ws too small): single-wave greedy NMS (proven correct)
// ---------------------------------------------------------------------------
__global__ __launch_bounds__(64) void nms_kernel(
    const float4* __restrict__ boxes_ws, float* __restrict__ scores_ws)
{
    const int img = blockIdx.x / NLVL;
    const int lvl = blockIdx.x % NLVL;
    const int K   = LVL_K[lvl];
    const size_t base = (size_t)img * TOTK + CAT_OFF[lvl];
    const int lane = threadIdx.x;

    __shared__ float4 bs[MAXK];
    for (int i = lane; i < K; i += 64) bs[i] = boxes_ws[base + i];
    __syncthreads();

    u64 myw = 0ull;
    for (int i = 0; i < K; ++i) {
        u64 wi = __shfl(myw, i >> 6);
        bool suppressed = (wi >> (i & 63)) & 1ull;
        if (!suppressed) {
            float4 bi = bs[i];
            float areaA = (bi.z - bi.x) * (bi.w - bi.y);
            for (int jb = i + 1; jb < K; jb += 64) {
                int j = jb + lane;
                bool over = false;
                if (j < K) over = iou_over(bi, areaA, bs[j]);
                u64 m = __ballot(over);
                int w0 = jb >> 6;
                int sh = jb & 63;
                if (lane == w0) myw |= (m << sh);
                if (sh && lane == (w0 + 1)) myw |= (m >> (64 - sh));
            }
        }
    }
    const int nch = (K + 63) >> 6;
    for (int c = 0; c < nch; ++c) {
        u64 w = __shfl(myw, c);
        int r = c * 64 + lane;
        if (r < K && ((w >> lane) & 1ull)) scores_ws[base + r] = NEGV;
    }
}

// ---------------------------------------------------------------------------
// final_topk: per-image exact top-1000 (proven code, unchanged)
// ---------------------------------------------------------------------------
__device__ void radix_topk_sorted(const float* __restrict__ s, int n, int k, int P,
                                  u32* hist, u32* chunk, u64* buf, u64* bcast, int* ibcast)
{
    const int tid = threadIdx.x;
    const int wid = tid >> 6;
    u64 pref = 0ull;
    int remk = k;
    int done = 0;
    const int SH[6] = {53, 42, 31, 20, 9, 0};
    const int WD[6] = {11, 11, 11, 11, 11, 9};

    for (int pass = 0; pass < 6 && !done; ++pass) {
        const int shift = SH[pass];
        const int nb    = 1 << WD[pass];
        for (int b = tid; b < 4 * 2048; b += T_BLK) hist[b] = 0u;
        __syncthreads();
        const u64 himask = (pass == 0) ? 0ull : (~0ull << SH[pass - 1]);
        u32* myh = hist + wid * 2048;
        for (int i0 = tid * 4; i0 < n; i0 += T_BLK * 4) {
            float4 v = *(const float4*)(s + i0);
            u64 k0 = make_key(v.x, i0);
            u64 k1 = make_key(v.y, i0 + 1);
            u64 k2 = make_key(v.z, i0 + 2);
            u64 k3 = make_key(v.w, i0 + 3);
            if ((k0 & himask) == pref) atomicAdd(&myh[(u32)(k0 >> shift) & (nb - 1)], 1u);
            if ((k1 & himask) == pref) atomicAdd(&myh[(u32)(k1 >> shift) & (nb - 1)], 1u);
            if ((k2 & himask) == pref) atomicAdd(&myh[(u32)(k2 >> shift) & (nb - 1)], 1u);
            if ((k3 & himask) == pref) atomicAdd(&myh[(u32)(k3 >> shift) & (nb - 1)], 1u);
        }
        __syncthreads();
        u32 csum = 0;
        for (int b = tid * 8; b < tid * 8 + 8; ++b)
            if (b < nb) csum += hist[b] + hist[2048 + b] + hist[4096 + b] + hist[6144 + b];
        chunk[tid] = csum;
        __syncthreads();
        if (tid == 0) {
            int cum = 0, cidx = 0;
            for (int c = 255; c >= 0; --c) {
                int cs = (int)chunk[c];
                if (cum + cs >= remk) { cidx = c; break; }
                cum += cs;
            }
            for (int b = cidx * 8 + 7; b >= cidx * 8; --b) {
                if (b >= nb) continue;
                int cb = (int)(hist[b] + hist[2048 + b] + hist[4096 + b] + hist[6144 + b]);
                if (cum + cb >= remk) {
                    bcast[0]  = pref | (((u64)(u32)b) << shift);
                    ibcast[0] = remk - cum;
                    ibcast[1] = (cb == (remk - cum)) ? 1 : 0;
                    break;
                }
                cum += cb;
            }
        }
        __syncthreads();
        pref = bcast[0];
        remk = ibcast[0];
        done = ibcast[1];
        __syncthreads();
    }
    const u64 thresh = pref;

    if (tid == 0) ibcast[2] = 0;
    __syncthreads();
    for (int i0 = tid * 4; i0 < n; i0 += T_BLK * 4) {
        float4 v = *(const float4*)(s + i0);
        u64 kk[4] = { make_key(v.x, i0), make_key(v.y, i0 + 1),
                      make_key(v.z, i0 + 2), make_key(v.w, i0 + 3) };
        #pragma unroll
        for (int q = 0; q < 4; ++q) {
            if (kk[q] >= thresh) {
                int pos = atomicAdd(&ibcast[2], 1);
                if (pos < P) buf[pos] = kk[q];
            }
        }
    }
    __syncthreads();
    for (int i = k + tid; i < P; i += T_BLK) buf[i] = 0ull;
    __syncthreads();

    for (int sz = 2; sz <= P; sz <<= 1) {
        for (int st = sz >> 1; st > 0; st >>= 1) {
            for (int i = tid; i < P; i += T_BLK) {
                int j = i ^ st;
                if (j > i) {
                    u64 a = buf[i];
                    u64 b = buf[j];
                    bool up = ((i & sz) == 0);
                    if ((a > b) == up) { buf[i] = b; buf[j] = a; }
                }
            }
            __syncthreads();
        }
    }
}

__global__ __launch_bounds__(T_BLK) void final_topk_kernel(
    const float4* __restrict__ boxes_ws, const float* __restrict__ scores_ws,
    float* __restrict__ out)
{
    const int img = blockIdx.x;
    const float* s = scores_ws + (size_t)img * TOTK;

    __shared__ u32 hist[4 * 2048];
    __shared__ u32 chunk[256];
    __shared__ u64 buf[1024];
    __shared__ u64 bcast;
    __shared__ int ibcast[4];

    radix_topk_sorted(s, TOTK, FINAL_K, 1024, hist, chunk, buf, &bcast, ibcast);

    const int tid = threadIdx.x;
    float4* outb = (float4*)out;               // fboxes: [16][1000][4]
    float*  outs = out + NIMG * FINAL_K * 4;   // fscores: [16][1000]
    for (int r = tid; r < FINAL_K; r += T_BLK) {
        u64 kk = buf[1024 - 1 - r];
        int idx = (int)(0xFFFFFFFFu - (unsigned)(kk & 0xFFFFFFFFull));
        outb[img * FINAL_K + r] = boxes_ws[(size_t)img * TOTK + idx];
        outs[img * FINAL_K + r] = s[idx];
    }
}

// ---------------------------------------------------------------------------
extern "C" void kernel_launch(void* const* d_in, const int* in_sizes, int n_in,
                              void* d_out, int out_size, void* d_ws, size_t ws_size,
                              hipStream_t stream)
{
    const float*  obj     = (const float*)d_in[0];
    const float4* deltas  = (const float4*)d_in[1];
    const float4* anchors = (const float4*)d_in[2];
    float* out = (float*)d_out;

    char* ws = (char*)d_ws;
    float4* boxes_ws  = (float4*)(ws + BOX_OFF);
    float*  scores_ws = (float*)(ws + SCORES_OFF);
    u32*    ghist     = (u32*)(ws + GHIST_OFF);
    u32*    cand_cnt  = (u32*)(ws + CNT_OFF);
    u32*    gbound    = (u32*)(ws + GB_OFF);
    u64*    cand      = (u64*)(ws + CAND_OFF);

    zero_kernel<<<512, T_BLK, 0, stream>>>(ghist);   // ghist + cand_cnt contiguous
    hist_kernel<<<NIMG * NSLICE, T_BLK, 0, stream>>>(obj, ghist);
    bound_kernel<<<NIMG * NLVL, T_BLK, 0, stream>>>(ghist, gbound);
    compact_kernel<<<NIMG * NSLICE, T_BLK, 0, stream>>>(obj, gbound, cand_cnt, cand);
    sort_decode_kernel<<<NIMG * NLVL, T_BLK, 0, stream>>>(deltas, anchors, cand_cnt, cand,
                                                          boxes_ws, scores_ws);

    if (ws_size >= MASK_OFF + MASK_BYTES) {
        u64* mask = (u64*)(ws + MASK_OFF);
        nms_mask_kernel<<<NIMG * NLVL * MAXT, T_BLK, 0, stream>>>(boxes_ws, mask);
        nms_scan_kernel<<<NIMG * NLVL, 64, 0, stream>>>(mask, scores_ws);
    } else {
        nms_kernel<<<NIMG * NLVL, 64, 0, stream>>>(boxes_ws, scores_ws);
    }

    final_topk_kernel<<<NIMG, T_BLK, 0, stream>>>(boxes_ws, scores_ws, out);
}